// Round 10
// baseline (281.057 us; speedup 1.0000x reference)
//
#include <hip/hip_runtime.h>
#include <hip/hip_bf16.h>

typedef __bf16 bf16;
typedef __bf16 bf16x4 __attribute__((ext_vector_type(4)));
typedef __bf16 bf16x8 __attribute__((ext_vector_type(8)));
typedef float f32x4 __attribute__((ext_vector_type(4)));

__device__ __forceinline__ void gload_lds16(const void* g, void* l) {
  __builtin_amdgcn_global_load_lds((__attribute__((address_space(1))) void*)(g),
                                   (__attribute__((address_space(3))) void*)(l), 16, 0, 0);
}
// raw 2^x (v_exp_f32 IS exp2)
__device__ __forceinline__ float fexp2(float x) {
  float r;
  asm volatile("v_exp_f32 %0, %1" : "=v"(r) : "v"(x));
  return r;
}
#define S_WAITCNT_VM(n) asm volatile("s_waitcnt vmcnt(" #n ")" ::: "memory")

// ---------------- diagnostic: encode ws_size into output if workspace too small ----
__global__ void k_diag(float* __restrict__ o, float v) { o[threadIdx.x] = v; }

// ---------------- fp32 -> bf16 convert (vectorized) ----------------
__global__ void k_cvt_bf16(const float* __restrict__ x, bf16* __restrict__ y, int n4) {
  int i = blockIdx.x * blockDim.x + threadIdx.x;
  if (i < n4) {
    float4 v = reinterpret_cast<const float4*>(x)[i];
    bf16x4 o = {(bf16)v.x, (bf16)v.y, (bf16)v.z, (bf16)v.w};
    reinterpret_cast<bf16x4*>(y)[i] = o;
  }
}

// ---------------- W (K x N fp32, row-major) -> Wt (N x K bf16) ----------------
__global__ void k_transpose_w(const float* __restrict__ W, bf16* __restrict__ Wt, int K, int N) {
  __shared__ float tile[32][33];
  int kb = blockIdx.x * 32, nb = blockIdx.y * 32;
  int tx = threadIdx.x & 31, ty = threadIdx.x >> 5;
#pragma unroll
  for (int i = 0; i < 32; i += 8)
    tile[ty + i][tx] = W[(size_t)(kb + ty + i) * N + nb + tx];
  __syncthreads();
#pragma unroll
  for (int i = 0; i < 32; i += 8)
    Wt[(size_t)(nb + ty + i) * K + kb + tx] = (bf16)tile[tx][ty + i];
}

// ---------------- V (cols 2560.. of Cqkv, stride 3072) -> Vt[b][kvh][HD][S] ----------------
__global__ void k_transpose_v(const bf16* __restrict__ Cq, bf16* __restrict__ Vt) {
  __shared__ bf16 tile[32][34];
  constexpr int S = 2048, CSTR = 3072;
  int sb = blockIdx.x * 32, db = blockIdx.y * 32, bh = blockIdx.z;  // bh = b*4+kvh
  int b = bh >> 2, kvh = bh & 3;
  int tx = threadIdx.x & 31, ty = threadIdx.x >> 5;
  const bf16* src = Cq + (size_t)b * S * CSTR + 2560 + kvh * 128;
#pragma unroll
  for (int i = 0; i < 32; i += 8)
    tile[ty + i][tx] = src[(size_t)(sb + ty + i) * CSTR + db + tx];
  __syncthreads();
  bf16* dst = Vt + (size_t)bh * 128 * S;
#pragma unroll
  for (int i = 0; i < 32; i += 8)
    dst[(size_t)(db + ty + i) * S + sb + tx] = tile[tx][ty + i];
}

// ---------------- 256x256 bf16 GEMM, 4-phase counted-vmcnt, 2D XCD supertile ----------
template <typename OT>
__global__ __launch_bounds__(512) void k_gemm3(const bf16* __restrict__ A,
                                               const bf16* __restrict__ B0,
                                               const bf16* __restrict__ B1, int nsplit,
                                               OT* __restrict__ C, int Ncols, int Kd) {
  __shared__ __align__(16) bf16 lds_[65536];  // 128 KiB
  char* lds = (char*)lds_;
  const int t = threadIdx.x, w = t >> 6, l = t & 63;
  const int lr = l & 15, lk = l >> 4;
  const int gx = gridDim.x;
  const int flat = blockIdx.y * gx + blockIdx.x;
  const int xcd = flat & 7, local = flat >> 3;
  const int mi = (xcd & 3) * (gx >> 2) + (local & ((gx >> 2) - 1));
  const int ni = (xcd >> 2) * (gridDim.y >> 1) + (local >> 2);
  const int m0 = mi * 256, n0 = ni * 256;
  const int wm = w >> 2, wn = w & 3;
  const bf16* Bt = (n0 < nsplit) ? B0 + (size_t)n0 * Kd : B1 + (size_t)(n0 - nsplit) * Kd;
  const int nkt = Kd >> 6;
  const int srow = l >> 2;
  const int lch = (l & 3) ^ ((srow + (srow >> 2)) & 3);
  auto stA = [&](int tile, int unit) {
    if (tile >= nkt) return;
    const bf16* s = A + (size_t)(m0 + unit * 64 + (w >> 1) * 16 + srow) * Kd +
                    (tile << 6) + (w & 1) * 32 + lch * 8;
    gload_lds16(s, lds + (tile & 1) * 32768 + unit * 8192 + w * 1024);
  };
  auto stB = [&](int tile, int grp) {
    if (tile >= nkt) return;
    const bf16* s = Bt + (size_t)((w >> 1) * 64 + grp * 16 + srow) * Kd +
                    (tile << 6) + (w & 1) * 32 + lch * 8;
    gload_lds16(s, lds + 65536 + (tile & 1) * 32768 + grp * 8192 + w * 1024);
  };
  const int rdoff = lr * 64 + ((lk ^ ((lr + (lr >> 2)) & 3)) << 4);

  f32x4 acc[8][4] = {};
  stA(0, 0); stA(0, 1); stA(0, 2); stA(0, 3);
  stB(0, 0);
  stA(1, 0); stB(0, 1); stA(1, 1); stB(0, 2); stA(1, 2); stB(0, 3);

  for (int kt = 0; kt < nkt; ++kt) {
    const int buf = kt & 1;
    const char* Ab = lds + buf * 32768;
    const char* Bb = lds + 65536 + buf * 32768;
    bf16x8 af[8][2];
#pragma unroll
    for (int p = 0; p < 4; ++p) {
      if (kt + 1 < nkt) { S_WAITCNT_VM(6); } else { S_WAITCNT_VM(0); }
      __builtin_amdgcn_sched_barrier(0);
      __builtin_amdgcn_s_barrier();
      __builtin_amdgcn_sched_barrier(0);
      if (p == 0) stA(kt + 1, 3); else stA(kt + 2, p - 1);
      stB(kt + 1, p);
      if (p == 0) {
#pragma unroll
        for (int i = 0; i < 8; ++i) {
          const char* ub = Ab + (wm * 2 + (i >> 2)) * 8192 + (i & 3) * 2048;
          af[i][0] = *reinterpret_cast<const bf16x8*>(ub + rdoff);
          af[i][1] = *reinterpret_cast<const bf16x8*>(ub + 1024 + rdoff);
        }
      }
      bf16x8 b0 = *reinterpret_cast<const bf16x8*>(Bb + p * 8192 + wn * 2048 + rdoff);
      bf16x8 b1 = *reinterpret_cast<const bf16x8*>(Bb + p * 8192 + wn * 2048 + 1024 + rdoff);
      __builtin_amdgcn_s_setprio(1);
#pragma unroll
      for (int i = 0; i < 8; ++i) {
        acc[i][p] = __builtin_amdgcn_mfma_f32_16x16x32_bf16(af[i][0], b0, acc[i][p], 0, 0, 0);
        acc[i][p] = __builtin_amdgcn_mfma_f32_16x16x32_bf16(af[i][1], b1, acc[i][p], 0, 0, 0);
      }
      __builtin_amdgcn_s_setprio(0);
      __builtin_amdgcn_sched_barrier(0);
    }
  }
#pragma unroll
  for (int i = 0; i < 8; ++i)
#pragma unroll
    for (int j = 0; j < 4; ++j)
#pragma unroll
      for (int r = 0; r < 4; ++r) {
        int row = m0 + wm * 128 + i * 16 + lk * 4 + r;
        int col = n0 + wn * 64 + j * 16 + lr;
        if constexpr (sizeof(OT) == 4)
          C[(size_t)row * Ncols + col] = acc[i][j][r];
        else
          C[(size_t)row * Ncols + col] = (bf16)acc[i][j][r];
      }
}

// ---------------- 2-phase GEMM (round-6 verified) for O projection ------
template <int BM, typename OT>
__global__ __launch_bounds__(512) void k_gemm2(const bf16* __restrict__ A, const bf16* __restrict__ Bt,
                                               OT* __restrict__ C, int N, int Kd) {
  constexpr int NA = (BM / 16) * 2;
  constexpr int NB = 16;
  constexpr int NST = NA + NB;
  constexpr int NSW = NST / 8;
  constexpr int WM = BM / 4;
  constexpr int RG = WM / 16;
  __shared__ __align__(16) bf16 sAB[2][NST * 512];
  const int t = threadIdx.x, w = t >> 6, l = t & 63;
  const int lr = l & 15, lk = l >> 4;
  const int gx = gridDim.x;
  const int nwg = gx * gridDim.y;
  const int flat = blockIdx.y * gx + blockIdx.x;
  const int vid = (flat & 7) * (nwg >> 3) + (flat >> 3);
  const int m0 = (vid % gx) * BM, n0 = (vid / gx) * 128;
  const int wm = w >> 1, wn = w & 1;
  const int srow = l >> 2;
  const int lchunk = (l & 3) ^ (((l >> 5) & 1) << 1);
  const int rdoff = lr * 64 + ((lk * 16) ^ ((lr >> 3) << 5));
  const int nkt = Kd >> 6;
  char* lds = (char*)sAB;

  auto stage = [&](int kt, int buf) {
    const int k0 = kt << 6;
#pragma unroll
    for (int u = 0; u < NSW; ++u) {
      const int s = w * NSW + u;
      const bf16* src;
      if (s < NA)
        src = A + (size_t)(m0 + (s >> 1) * 16 + srow) * Kd + k0 + (s & 1) * 32 + lchunk * 8;
      else
        src = Bt + (size_t)(n0 + ((s - NA) >> 1) * 16 + srow) * Kd + k0 + ((s - NA) & 1) * 32 + lchunk * 8;
      gload_lds16(src, lds + buf * (NST * 1024) + s * 1024);
    }
  };

  f32x4 acc[RG][4] = {};
  stage(0, 0);
  stage(1, 1);
  if constexpr (NSW == 6) S_WAITCNT_VM(6); else S_WAITCNT_VM(4);
  __builtin_amdgcn_s_barrier();
  int c = 0;
  for (int kt = 0; kt < nkt; ++kt) {
    __builtin_amdgcn_sched_barrier(0);
    const char* base = lds + c * (NST * 1024);
    bf16x8 af[RG][2], bfr[4][2];
#pragma unroll
    for (int i = 0; i < RG; ++i)
#pragma unroll
      for (int kk = 0; kk < 2; ++kk)
        af[i][kk] = *reinterpret_cast<const bf16x8*>(base + ((wm * RG + i) * 2 + kk) * 1024 + rdoff);
#pragma unroll
    for (int j = 0; j < 4; ++j)
#pragma unroll
      for (int kk = 0; kk < 2; ++kk)
        bfr[j][kk] = *reinterpret_cast<const bf16x8*>(base + (NA + (wn * 4 + j) * 2 + kk) * 1024 + rdoff);
    __builtin_amdgcn_s_setprio(1);
#pragma unroll
    for (int i = 0; i < RG; ++i)
#pragma unroll
      for (int j = 0; j < 4; ++j) {
        acc[i][j] = __builtin_amdgcn_mfma_f32_16x16x32_bf16(af[i][0], bfr[j][0], acc[i][j], 0, 0, 0);
        acc[i][j] = __builtin_amdgcn_mfma_f32_16x16x32_bf16(af[i][1], bfr[j][1], acc[i][j], 0, 0, 0);
      }
    __builtin_amdgcn_s_setprio(0);
    __builtin_amdgcn_sched_barrier(0);
    asm volatile("" ::: "memory");
    __builtin_amdgcn_s_barrier();
    if (kt + 2 < nkt) stage(kt + 2, c);
    if (kt + 1 < nkt) {
      if (kt + 2 < nkt) {
        if constexpr (NSW == 6) S_WAITCNT_VM(6); else S_WAITCNT_VM(4);
      } else {
        S_WAITCNT_VM(0);
      }
      asm volatile("" ::: "memory");
      __builtin_amdgcn_s_barrier();
    }
    c ^= 1;
  }
#pragma unroll
  for (int i = 0; i < RG; ++i)
#pragma unroll
    for (int j = 0; j < 4; ++j)
#pragma unroll
      for (int r = 0; r < 4; ++r) {
        int row = m0 + wm * WM + i * 16 + lk * 4 + r;
        int col = n0 + wn * 64 + j * 16 + lr;
        if constexpr (sizeof(OT) == 4)
          C[(size_t)row * N + col] = acc[i][j][r];
        else
          C[(size_t)row * N + col] = (bf16)acc[i][j][r];
      }
}

// ---------------- RoPE in place (optionally folds score scale into Q) ----------------
__global__ void k_rope(bf16* __restrict__ X, const float* __restrict__ cs, const float* __restrict__ sn,
                       int nh, int rowstride, float scale, int total) {
  int idx = blockIdx.x * blockDim.x + threadIdx.x;
  if (idx >= total) return;
  int d = idx & 63;
  int th = idx >> 6;
  int h = th % nh;
  int tok = th / nh;
  size_t base = (size_t)tok * rowstride + h * 128;
  float c = cs[tok * 128 + d], s = sn[tok * 128 + d];
  float x1 = (float)X[base + d];
  float x2 = (float)X[base + d + 64];
  X[base + d] = (bf16)((x1 * c - x2 * s) * scale);
  X[base + d + 64] = (bf16)((x2 * c + x1 * s) * scale);
}

// ---------------- causal flash attention, 32q/wave + round-5 pipeline ----------------
// Block = 4 waves x 32q = 128-q tile; 512 blocks (16 qt x 32 bh), LPT (heavy qt first),
// XCD swizzle (per-XCD KV 1MB L2-resident). K/V double-buffered; prefetch(t+1) issued
// BEFORE compute(t); ONE __syncthreads per tile (round-5 verified structure).
// sP reused sequentially for both 16-row groups (DS ops in-order per wave -> WAR safe).
// LDS 73KB -> 2 blocks/CU. Fully-masked wave-tiles skip compute, keep stage+barrier.
__global__ __launch_bounds__(256) void k_attn(const bf16* __restrict__ Q, const bf16* __restrict__ KV,
                                              const bf16* __restrict__ Vt, bf16* __restrict__ O) {
  constexpr int S = 2048, HD = 128, QSTR = 3072, OSTR = 2048;
  __shared__ __align__(16) bf16 sK[2][64 * 128];
  __shared__ __align__(16) bf16 sV[2][128 * 64];
  __shared__ __align__(16) bf16 sP[4][16][72];
  const int bid = blockIdx.x;
  const int vid = (bid & 7) * 64 + (bid >> 3);  // XCD swizzle
  const int qt = 15 - (vid & 15);               // heavy q-tiles dispatch first (LPT)
  const int bh = vid >> 4;
  const int h = bh & 15, b = bh >> 4;
  const int t = threadIdx.x, w = t >> 6, l = t & 63;
  const int lr = l & 15, lk = l >> 4;
  const int kvh = h >> 2;
  const int swz = (lr & 7) << 4;

  const char* kbase = (const char*)(KV + (size_t)b * S * QSTR + kvh * HD);
  const int krow_l = w * 16 + (l >> 4);
  const int kcol_l = (l & 15) << 4;
  const char* vtbase = (const char*)(Vt + (size_t)(b * 4 + kvh) * HD * S);
  const int vrow_l = w * 32 + (l >> 3);
  const int vcol_l = (l & 7) << 4;
  char* sKb = (char*)sK;
  char* sVb = (char*)sV;
  auto stage = [&](int kvb, int buf) {
#pragma unroll
    for (int c = 0; c < 4; ++c) {
      const int krow = krow_l + c * 4;
      gload_lds16(kbase + (size_t)(kvb + krow) * (QSTR * 2) + (kcol_l ^ ((krow & 7) << 4)),
                  sKb + buf * 16384 + (w * 4 + c) * 1024);
      const int vrow = vrow_l + c * 8;
      gload_lds16(vtbase + (size_t)vrow * (S * 2) + kvb * 2 + (vcol_l ^ ((vrow & 7) << 4)),
                  sVb + buf * 16384 + (w * 4 + c) * 1024);
    }
  };

  const int qw = qt * 128 + w * 32;  // this wave's 32 q-rows
  const int qlast = qw + 31;
  bf16x8 qf[2][4];
#pragma unroll
  for (int rg = 0; rg < 2; ++rg) {
    const bf16* Qp = Q + (size_t)(b * S + qw + rg * 16 + lr) * QSTR + h * HD + lk * 8;
#pragma unroll
    for (int i = 0; i < 4; ++i) qf[rg][i] = *reinterpret_cast<const bf16x8*>(Qp + i * 32);
  }
  f32x4 oacc[2][8] = {};
  float mrow[2][4] = {{-3e38f, -3e38f, -3e38f, -3e38f}, {-3e38f, -3e38f, -3e38f, -3e38f}};
  float lsum[2][4] = {};
  const int ntiles = (qt + 1) * 2;
  int cur = 0;
  stage(0, 0);
  __syncthreads();  // tile 0 resident
  for (int tt = 0; tt < ntiles; ++tt) {
    const int kvb = tt * 64;
    if (tt + 1 < ntiles) stage(kvb + 64, cur ^ 1);  // prefetch hides under compute
    const char* sKc = sKb + cur * 16384;
    const char* sVc = sVb + cur * 16384;
    if (kvb <= qlast) {  // skip fully-masked wave-tiles (stage+barrier still run)
      // ---- QK^T: 32q x 64kv ----
      float pm[2][4][4];
#pragma unroll
      for (int c = 0; c < 4; ++c) {
        f32x4 s0 = {}, s1 = {};
#pragma unroll
        for (int kf = 0; kf < 4; ++kf) {
          bf16x8 kf8 = *reinterpret_cast<const bf16x8*>(
              sKc + (c * 16 + lr) * 256 + (((kf * 64) + (lk << 4)) ^ swz));
          s0 = __builtin_amdgcn_mfma_f32_16x16x32_bf16(qf[0][kf], kf8, s0, 0, 0, 0);
          s1 = __builtin_amdgcn_mfma_f32_16x16x32_bf16(qf[1][kf], kf8, s1, 0, 0, 0);
        }
#pragma unroll
        for (int r = 0; r < 4; ++r) { pm[0][c][r] = s0[r]; pm[1][c][r] = s1[r]; }
      }
      // ---- causal mask (wave-uniform branch; near-diagonal only) ----
      if (kvb + 63 > qw) {
#pragma unroll
        for (int rg = 0; rg < 2; ++rg)
#pragma unroll
          for (int c = 0; c < 4; ++c) {
            const int col = kvb + c * 16 + lr;
#pragma unroll
            for (int r = 0; r < 4; ++r)
              if (col > qw + rg * 16 + lk * 4 + r) pm[rg][c][r] = -3e38f;
          }
      }
      // ---- defer-max online softmax ----
      float pmax[2][4];
#pragma unroll
      for (int rg = 0; rg < 2; ++rg)
#pragma unroll
        for (int r = 0; r < 4; ++r)
          pmax[rg][r] = fmaxf(fmaxf(pm[rg][0][r], pm[rg][1][r]), fmaxf(pm[rg][2][r], pm[rg][3][r]));
      bool hi = false;
#pragma unroll
      for (int rg = 0; rg < 2; ++rg)
#pragma unroll
        for (int r = 0; r < 4; ++r) hi |= (pmax[rg][r] > mrow[rg][r] + 8.f);
      if (__any(hi)) {
        float mx[2][4];
#pragma unroll
        for (int rg = 0; rg < 2; ++rg)
#pragma unroll
          for (int r = 0; r < 4; ++r) mx[rg][r] = pmax[rg][r];
#pragma unroll
        for (int off = 1; off < 16; off <<= 1)
#pragma unroll
          for (int rg = 0; rg < 2; ++rg)
#pragma unroll
            for (int r = 0; r < 4; ++r) mx[rg][r] = fmaxf(mx[rg][r], __shfl_xor(mx[rg][r], off));
#pragma unroll
        for (int rg = 0; rg < 2; ++rg)
#pragma unroll
          for (int r = 0; r < 4; ++r) {
            float mn = fmaxf(mrow[rg][r], mx[rg][r]);
            float fac = fexp2(mrow[rg][r] - mn);
            mrow[rg][r] = mn;
            lsum[rg][r] *= fac;
#pragma unroll
            for (int ch = 0; ch < 8; ++ch) oacc[rg][ch][r] *= fac;
          }
      }
#pragma unroll
      for (int rg = 0; rg < 2; ++rg) {
#pragma unroll
        for (int c = 0; c < 4; ++c)
#pragma unroll
          for (int r = 0; r < 4; ++r) pm[rg][c][r] = fexp2(pm[rg][c][r] - mrow[rg][r]);
#pragma unroll
        for (int r = 0; r < 4; ++r)
          lsum[rg][r] += (pm[rg][0][r] + pm[rg][1][r]) + (pm[rg][2][r] + pm[rg][3][r]);
      }
      // ---- P: D-frag -> A-frag via per-wave sP, reused for rg=0 then rg=1 ----
      bf16x8 pf[2][2];
#pragma unroll
      for (int rg = 0; rg < 2; ++rg) {
#pragma unroll
        for (int c = 0; c < 4; ++c)
#pragma unroll
          for (int r = 0; r < 4; ++r) sP[w][lk * 4 + r][c * 16 + lr] = (bf16)pm[rg][c][r];
        pf[rg][0] = *reinterpret_cast<const bf16x8*>(&sP[w][lr][lk * 8]);
        pf[rg][1] = *reinterpret_cast<const bf16x8*>(&sP[w][lr][32 + lk * 8]);
      }
      // ---- PV: out[32q][128d] += P[32q][64kv] * V^T ----
#pragma unroll
      for (int ch = 0; ch < 8; ++ch) {
        bf16x8 vf0 = *reinterpret_cast<const bf16x8*>(
            sVc + (ch * 16 + lr) * 128 + ((lk << 4) ^ swz));
        bf16x8 vf1 = *reinterpret_cast<const bf16x8*>(
            sVc + (ch * 16 + lr) * 128 + ((64 + (lk << 4)) ^ swz));
        oacc[0][ch] = __builtin_amdgcn_mfma_f32_16x16x32_bf16(pf[0][0], vf0, oacc[0][ch], 0, 0, 0);
        oacc[0][ch] = __builtin_amdgcn_mfma_f32_16x16x32_bf16(pf[0][1], vf1, oacc[0][ch], 0, 0, 0);
        oacc[1][ch] = __builtin_amdgcn_mfma_f32_16x16x32_bf16(pf[1][0], vf0, oacc[1][ch], 0, 0, 0);
        oacc[1][ch] = __builtin_amdgcn_mfma_f32_16x16x32_bf16(pf[1][1], vf1, oacc[1][ch], 0, 0, 0);
      }
    }
    __syncthreads();  // single barrier per tile: drains prefetch, fences buffer reuse
    cur ^= 1;
  }
  // final lsum reduce, normalize, write
#pragma unroll
  for (int off = 1; off < 16; off <<= 1)
#pragma unroll
    for (int rg = 0; rg < 2; ++rg)
#pragma unroll
      for (int r = 0; r < 4; ++r) lsum[rg][r] += __shfl_xor(lsum[rg][r], off);
#pragma unroll
  for (int rg = 0; rg < 2; ++rg) {
    float inv[4];
#pragma unroll
    for (int r = 0; r < 4; ++r) inv[r] = 1.0f / lsum[rg][r];
    bf16* Op = O + (size_t)(b * S + qw + rg * 16) * OSTR + h * HD;
#pragma unroll
    for (int ch = 0; ch < 8; ++ch)
#pragma unroll
      for (int r = 0; r < 4; ++r)
        Op[(size_t)(lk * 4 + r) * OSTR + ch * 16 + lr] = (bf16)(oacc[rg][ch][r] * inv[r]);
  }
}

extern "C" void kernel_launch(void* const* d_in, const int* in_sizes, int n_in,
                              void* d_out, int out_size, void* d_ws, size_t ws_size,
                              hipStream_t stream) {
  const float* hs = (const float*)d_in[0];
  // d_in[1] = attention_mask: pure causal, applied analytically
  const float* cosb = (const float*)d_in[2];
  const float* sinb = (const float*)d_in[3];
  const float* Wq = (const float*)d_in[4];
  const float* Wk = (const float*)d_in[5];
  const float* Wv = (const float*)d_in[6];
  const float* Wo = (const float*)d_in[7];
  float* out = (float*)d_out;

  constexpr int B = 2, S = 2048, H = 2048, NH = 16, NKV = 4, HD = 128;
  constexpr int T = B * S;
  constexpr size_t MB = 1024 * 1024;

  // Workspace plan (d_ws 24 MiB):
  //   d_ws[ 0:16M) : Xb (bf16 X), reused as Ob after QKV projection
  //   d_ws[16:24M) : WtQ (8MB) -> later WtO (8MB)
  //   d_out[ 0:24M): Cqkv bf16 [4096][3072] (Q | K | V)
  //   d_out[24:28M): Vt [8][128][2048]
  //   d_out[28:32M): WtKV [1024][2048]
  const size_t ws_need = 24 * MB;
  if (ws_size < ws_need) {
    k_diag<<<1, 64, 0, stream>>>(out, 1000.0f + (float)(ws_size / MB));
    return;
  }
  bf16* Xb = (bf16*)d_ws;
  bf16* WtQ = (bf16*)((char*)d_ws + 16 * MB);  // also WtO slot later
  bf16* Ob = Xb;
  bf16* Cqkv = (bf16*)d_out;
  bf16* Vtb = (bf16*)((char*)d_out + 24 * MB);
  bf16* WtKV = (bf16*)((char*)d_out + 28 * MB);

  k_cvt_bf16<<<T * H / 4 / 256, 256, 0, stream>>>(hs, Xb, T * H / 4);

  k_transpose_w<<<dim3(H / 32, H / 32), 256, 0, stream>>>(Wq, WtQ, H, H);
  k_transpose_w<<<dim3(H / 32, (NKV * HD) / 32), 256, 0, stream>>>(Wk, WtKV, H, NKV * HD);
  k_transpose_w<<<dim3(H / 32, (NKV * HD) / 32), 256, 0, stream>>>(Wv, WtKV + (size_t)(NKV * HD) * H, H, NKV * HD);

  // fused QKV projection: C[4096][3072], grid 16x12 = 192 blocks, 2D XCD supertile
  k_gemm3<bf16><<<dim3(16, 12), 512, 0, stream>>>(Xb, WtQ, WtKV, 2048, Cqkv, 3072, H);

  // V -> Vt (V gets no RoPE)
  k_transpose_v<<<dim3(S / 32, HD / 32, B * NKV), 256, 0, stream>>>(Cqkv, Vtb);

  // RoPE; Q folds log2(e)/sqrt(HD) so QK^T lands in log2 domain
  const float qscale = 0.12751743f;  // log2(e) / sqrt(128)
  k_rope<<<(T * NH * 64) / 256, 256, 0, stream>>>(Cqkv, cosb, sinb, NH, 3072, qscale, T * NH * 64);
  k_rope<<<(T * NKV * 64) / 256, 256, 0, stream>>>(Cqkv + 2048, cosb, sinb, NKV, 3072, 1.0f, T * NKV * 64);

  // Attention: reads Q/K (Cqkv) + Vt, writes Ob into d_ws (Xb dead)
  k_attn<<<512, 256, 0, stream>>>(Cqkv, Cqkv + 2048, Vtb, Ob);

  // O projection: reads only d_ws (Ob, WtO), writes all of d_out; full 256-block fill
  k_transpose_w<<<dim3(H / 32, H / 32), 256, 0, stream>>>(Wo, WtQ, H, H);
  k_gemm2<256, float><<<dim3(16, 16), 512, 0, stream>>>(Ob, WtQ, out, H, H);
}

// Round 11
// 234.213 us; speedup vs baseline: 1.2000x; 1.2000x over previous
//
#include <hip/hip_runtime.h>
#include <hip/hip_bf16.h>

typedef __bf16 bf16;
typedef __bf16 bf16x4 __attribute__((ext_vector_type(4)));
typedef __bf16 bf16x8 __attribute__((ext_vector_type(8)));
typedef float f32x4 __attribute__((ext_vector_type(4)));

__device__ __forceinline__ void gload_lds16(const void* g, void* l) {
  __builtin_amdgcn_global_load_lds((__attribute__((address_space(1))) void*)(g),
                                   (__attribute__((address_space(3))) void*)(l), 16, 0, 0);
}
// raw 2^x (v_exp_f32 IS exp2)
__device__ __forceinline__ float fexp2(float x) {
  float r;
  asm volatile("v_exp_f32 %0, %1" : "=v"(r) : "v"(x));
  return r;
}
#define S_WAITCNT_VM(n) asm volatile("s_waitcnt vmcnt(" #n ")" ::: "memory")

// ---------------- diagnostic: encode ws_size into output if workspace too small ----
__global__ void k_diag(float* __restrict__ o, float v) { o[threadIdx.x] = v; }

// ---------------- fp32 -> bf16 convert (vectorized) ----------------
__global__ void k_cvt_bf16(const float* __restrict__ x, bf16* __restrict__ y, int n4) {
  int i = blockIdx.x * blockDim.x + threadIdx.x;
  if (i < n4) {
    float4 v = reinterpret_cast<const float4*>(x)[i];
    bf16x4 o = {(bf16)v.x, (bf16)v.y, (bf16)v.z, (bf16)v.w};
    reinterpret_cast<bf16x4*>(y)[i] = o;
  }
}

// ---------------- W (K x N fp32, row-major) -> Wt (N x K bf16) ----------------
__global__ void k_transpose_w(const float* __restrict__ W, bf16* __restrict__ Wt, int K, int N) {
  __shared__ float tile[32][33];
  int kb = blockIdx.x * 32, nb = blockIdx.y * 32;
  int tx = threadIdx.x & 31, ty = threadIdx.x >> 5;
#pragma unroll
  for (int i = 0; i < 32; i += 8)
    tile[ty + i][tx] = W[(size_t)(kb + ty + i) * N + nb + tx];
  __syncthreads();
#pragma unroll
  for (int i = 0; i < 32; i += 8)
    Wt[(size_t)(nb + ty + i) * K + kb + tx] = (bf16)tile[tx][ty + i];
}

// ---------------- V (cols 2560.. of Cqkv, stride 3072) -> Vt[b][kvh][HD][S] ----------------
__global__ void k_transpose_v(const bf16* __restrict__ Cq, bf16* __restrict__ Vt) {
  __shared__ bf16 tile[32][34];
  constexpr int S = 2048, CSTR = 3072;
  int sb = blockIdx.x * 32, db = blockIdx.y * 32, bh = blockIdx.z;  // bh = b*4+kvh
  int b = bh >> 2, kvh = bh & 3;
  int tx = threadIdx.x & 31, ty = threadIdx.x >> 5;
  const bf16* src = Cq + (size_t)b * S * CSTR + 2560 + kvh * 128;
#pragma unroll
  for (int i = 0; i < 32; i += 8)
    tile[ty + i][tx] = src[(size_t)(sb + ty + i) * CSTR + db + tx];
  __syncthreads();
  bf16* dst = Vt + (size_t)bh * 128 * S;
#pragma unroll
  for (int i = 0; i < 32; i += 8)
    dst[(size_t)(db + ty + i) * S + sb + tx] = tile[tx][ty + i];
}

// ---------------- 256x256 bf16 GEMM, 4-phase counted-vmcnt, 2D XCD supertile ----------
template <typename OT>
__global__ __launch_bounds__(512) void k_gemm3(const bf16* __restrict__ A,
                                               const bf16* __restrict__ B0,
                                               const bf16* __restrict__ B1, int nsplit,
                                               OT* __restrict__ C, int Ncols, int Kd) {
  __shared__ __align__(16) bf16 lds_[65536];  // 128 KiB
  char* lds = (char*)lds_;
  const int t = threadIdx.x, w = t >> 6, l = t & 63;
  const int lr = l & 15, lk = l >> 4;
  const int gx = gridDim.x;
  const int flat = blockIdx.y * gx + blockIdx.x;
  const int xcd = flat & 7, local = flat >> 3;
  const int mi = (xcd & 3) * (gx >> 2) + (local & ((gx >> 2) - 1));
  const int ni = (xcd >> 2) * (gridDim.y >> 1) + (local >> 2);
  const int m0 = mi * 256, n0 = ni * 256;
  const int wm = w >> 2, wn = w & 3;
  const bf16* Bt = (n0 < nsplit) ? B0 + (size_t)n0 * Kd : B1 + (size_t)(n0 - nsplit) * Kd;
  const int nkt = Kd >> 6;
  const int srow = l >> 2;
  const int lch = (l & 3) ^ ((srow + (srow >> 2)) & 3);
  auto stA = [&](int tile, int unit) {
    if (tile >= nkt) return;
    const bf16* s = A + (size_t)(m0 + unit * 64 + (w >> 1) * 16 + srow) * Kd +
                    (tile << 6) + (w & 1) * 32 + lch * 8;
    gload_lds16(s, lds + (tile & 1) * 32768 + unit * 8192 + w * 1024);
  };
  auto stB = [&](int tile, int grp) {
    if (tile >= nkt) return;
    const bf16* s = Bt + (size_t)((w >> 1) * 64 + grp * 16 + srow) * Kd +
                    (tile << 6) + (w & 1) * 32 + lch * 8;
    gload_lds16(s, lds + 65536 + (tile & 1) * 32768 + grp * 8192 + w * 1024);
  };
  const int rdoff = lr * 64 + ((lk ^ ((lr + (lr >> 2)) & 3)) << 4);

  f32x4 acc[8][4] = {};
  stA(0, 0); stA(0, 1); stA(0, 2); stA(0, 3);
  stB(0, 0);
  stA(1, 0); stB(0, 1); stA(1, 1); stB(0, 2); stA(1, 2); stB(0, 3);

  for (int kt = 0; kt < nkt; ++kt) {
    const int buf = kt & 1;
    const char* Ab = lds + buf * 32768;
    const char* Bb = lds + 65536 + buf * 32768;
    bf16x8 af[8][2];
#pragma unroll
    for (int p = 0; p < 4; ++p) {
      if (kt + 1 < nkt) { S_WAITCNT_VM(6); } else { S_WAITCNT_VM(0); }
      __builtin_amdgcn_sched_barrier(0);
      __builtin_amdgcn_s_barrier();
      __builtin_amdgcn_sched_barrier(0);
      if (p == 0) stA(kt + 1, 3); else stA(kt + 2, p - 1);
      stB(kt + 1, p);
      if (p == 0) {
#pragma unroll
        for (int i = 0; i < 8; ++i) {
          const char* ub = Ab + (wm * 2 + (i >> 2)) * 8192 + (i & 3) * 2048;
          af[i][0] = *reinterpret_cast<const bf16x8*>(ub + rdoff);
          af[i][1] = *reinterpret_cast<const bf16x8*>(ub + 1024 + rdoff);
        }
      }
      bf16x8 b0 = *reinterpret_cast<const bf16x8*>(Bb + p * 8192 + wn * 2048 + rdoff);
      bf16x8 b1 = *reinterpret_cast<const bf16x8*>(Bb + p * 8192 + wn * 2048 + 1024 + rdoff);
      __builtin_amdgcn_s_setprio(1);
#pragma unroll
      for (int i = 0; i < 8; ++i) {
        acc[i][p] = __builtin_amdgcn_mfma_f32_16x16x32_bf16(af[i][0], b0, acc[i][p], 0, 0, 0);
        acc[i][p] = __builtin_amdgcn_mfma_f32_16x16x32_bf16(af[i][1], b1, acc[i][p], 0, 0, 0);
      }
      __builtin_amdgcn_s_setprio(0);
      __builtin_amdgcn_sched_barrier(0);
    }
  }
#pragma unroll
  for (int i = 0; i < 8; ++i)
#pragma unroll
    for (int j = 0; j < 4; ++j)
#pragma unroll
      for (int r = 0; r < 4; ++r) {
        int row = m0 + wm * 128 + i * 16 + lk * 4 + r;
        int col = n0 + wn * 64 + j * 16 + lr;
        if constexpr (sizeof(OT) == 4)
          C[(size_t)row * Ncols + col] = acc[i][j][r];
        else
          C[(size_t)row * Ncols + col] = (bf16)acc[i][j][r];
      }
}

// ---------------- 2-phase GEMM (round-6 verified) for O projection ------
template <int BM, typename OT>
__global__ __launch_bounds__(512) void k_gemm2(const bf16* __restrict__ A, const bf16* __restrict__ Bt,
                                               OT* __restrict__ C, int N, int Kd) {
  constexpr int NA = (BM / 16) * 2;
  constexpr int NB = 16;
  constexpr int NST = NA + NB;
  constexpr int NSW = NST / 8;
  constexpr int WM = BM / 4;
  constexpr int RG = WM / 16;
  __shared__ __align__(16) bf16 sAB[2][NST * 512];
  const int t = threadIdx.x, w = t >> 6, l = t & 63;
  const int lr = l & 15, lk = l >> 4;
  const int gx = gridDim.x;
  const int nwg = gx * gridDim.y;
  const int flat = blockIdx.y * gx + blockIdx.x;
  const int vid = (flat & 7) * (nwg >> 3) + (flat >> 3);
  const int m0 = (vid % gx) * BM, n0 = (vid / gx) * 128;
  const int wm = w >> 1, wn = w & 1;
  const int srow = l >> 2;
  const int lchunk = (l & 3) ^ (((l >> 5) & 1) << 1);
  const int rdoff = lr * 64 + ((lk * 16) ^ ((lr >> 3) << 5));
  const int nkt = Kd >> 6;
  char* lds = (char*)sAB;

  auto stage = [&](int kt, int buf) {
    const int k0 = kt << 6;
#pragma unroll
    for (int u = 0; u < NSW; ++u) {
      const int s = w * NSW + u;
      const bf16* src;
      if (s < NA)
        src = A + (size_t)(m0 + (s >> 1) * 16 + srow) * Kd + k0 + (s & 1) * 32 + lchunk * 8;
      else
        src = Bt + (size_t)(n0 + ((s - NA) >> 1) * 16 + srow) * Kd + k0 + ((s - NA) & 1) * 32 + lchunk * 8;
      gload_lds16(src, lds + buf * (NST * 1024) + s * 1024);
    }
  };

  f32x4 acc[RG][4] = {};
  stage(0, 0);
  stage(1, 1);
  if constexpr (NSW == 6) S_WAITCNT_VM(6); else S_WAITCNT_VM(4);
  __builtin_amdgcn_s_barrier();
  int c = 0;
  for (int kt = 0; kt < nkt; ++kt) {
    __builtin_amdgcn_sched_barrier(0);
    const char* base = lds + c * (NST * 1024);
    bf16x8 af[RG][2], bfr[4][2];
#pragma unroll
    for (int i = 0; i < RG; ++i)
#pragma unroll
      for (int kk = 0; kk < 2; ++kk)
        af[i][kk] = *reinterpret_cast<const bf16x8*>(base + ((wm * RG + i) * 2 + kk) * 1024 + rdoff);
#pragma unroll
    for (int j = 0; j < 4; ++j)
#pragma unroll
      for (int kk = 0; kk < 2; ++kk)
        bfr[j][kk] = *reinterpret_cast<const bf16x8*>(base + (NA + (wn * 4 + j) * 2 + kk) * 1024 + rdoff);
    __builtin_amdgcn_s_setprio(1);
#pragma unroll
    for (int i = 0; i < RG; ++i)
#pragma unroll
      for (int j = 0; j < 4; ++j) {
        acc[i][j] = __builtin_amdgcn_mfma_f32_16x16x32_bf16(af[i][0], bfr[j][0], acc[i][j], 0, 0, 0);
        acc[i][j] = __builtin_amdgcn_mfma_f32_16x16x32_bf16(af[i][1], bfr[j][1], acc[i][j], 0, 0, 0);
      }
    __builtin_amdgcn_s_setprio(0);
    __builtin_amdgcn_sched_barrier(0);
    asm volatile("" ::: "memory");
    __builtin_amdgcn_s_barrier();
    if (kt + 2 < nkt) stage(kt + 2, c);
    if (kt + 1 < nkt) {
      if (kt + 2 < nkt) {
        if constexpr (NSW == 6) S_WAITCNT_VM(6); else S_WAITCNT_VM(4);
      } else {
        S_WAITCNT_VM(0);
      }
      asm volatile("" ::: "memory");
      __builtin_amdgcn_s_barrier();
    }
    c ^= 1;
  }
#pragma unroll
  for (int i = 0; i < RG; ++i)
#pragma unroll
    for (int j = 0; j < 4; ++j)
#pragma unroll
      for (int r = 0; r < 4; ++r) {
        int row = m0 + wm * WM + i * 16 + lk * 4 + r;
        int col = n0 + wn * 64 + j * 16 + lr;
        if constexpr (sizeof(OT) == 4)
          C[(size_t)row * N + col] = acc[i][j][r];
        else
          C[(size_t)row * N + col] = (bf16)acc[i][j][r];
      }
}

// ---------------- RoPE in place (optionally folds score scale into Q) ----------------
__global__ void k_rope(bf16* __restrict__ X, const float* __restrict__ cs, const float* __restrict__ sn,
                       int nh, int rowstride, float scale, int total) {
  int idx = blockIdx.x * blockDim.x + threadIdx.x;
  if (idx >= total) return;
  int d = idx & 63;
  int th = idx >> 6;
  int h = th % nh;
  int tok = th / nh;
  size_t base = (size_t)tok * rowstride + h * 128;
  float c = cs[tok * 128 + d], s = sn[tok * 128 + d];
  float x1 = (float)X[base + d];
  float x2 = (float)X[base + d + 64];
  X[base + d] = (bf16)((x1 * c - x2 * s) * scale);
  X[base + d + 64] = (bf16)((x2 * c + x1 * s) * scale);
}

// ---------------- causal flash attention: 32q/wave, paired q-tiles (uniform load) ----
// Block = 4 waves x 32q = 128-q tile; handles segments {p, 15-p} -> exactly 34 kv-tiles
// per block. Grid 256 = 8 pairs x 32 bh, 1 block/CU (no queue -> uniformity IS the
// balance). XCD swizzle: vid=(bid&7)*32+(bid>>3) -> each XCD owns one (b,kvh):
// K+V 1MB + Q 2MB L2-resident. K/V double-buffered, prefetch(t+1) before compute(t),
// ONE __syncthreads per tile (round-5 verified pipeline). 32q/wave halves the per-CU
// DS-pipe traffic per unit work vs 16q/wave (attn is LDS-BW bound: ~1.5k cy/tile of
// ds_read_b128 per block). sP reused for both 16-row groups (per-wave DS in-order).
__global__ __launch_bounds__(256) void k_attn(const bf16* __restrict__ Q, const bf16* __restrict__ KV,
                                              const bf16* __restrict__ Vt, bf16* __restrict__ O) {
  constexpr int S = 2048, HD = 128, QSTR = 3072, OSTR = 2048;
  __shared__ __align__(16) bf16 sK[2][64 * 128];
  __shared__ __align__(16) bf16 sV[2][128 * 64];
  __shared__ __align__(16) bf16 sP[4][16][72];
  const int bid = blockIdx.x;
  const int vid = (bid & 7) * 32 + (bid >> 3);  // XCD swizzle: one (b,kvh) per XCD
  const int p = vid & 7, bh = vid >> 3;
  const int h = bh & 15, b = bh >> 4;
  const int t = threadIdx.x, w = t >> 6, l = t & 63;
  const int lr = l & 15, lk = l >> 4;
  const int kvh = h >> 2;
  const int swz = (lr & 7) << 4;

  const char* kbase = (const char*)(KV + (size_t)b * S * QSTR + kvh * HD);
  const int krow_l = w * 16 + (l >> 4);
  const int kcol_l = (l & 15) << 4;
  const char* vtbase = (const char*)(Vt + (size_t)(b * 4 + kvh) * HD * S);
  const int vrow_l = w * 32 + (l >> 3);
  const int vcol_l = (l & 7) << 4;
  char* sKb = (char*)sK;
  char* sVb = (char*)sV;
  auto stage = [&](int kvb, int buf) {
#pragma unroll
    for (int c = 0; c < 4; ++c) {
      const int krow = krow_l + c * 4;
      gload_lds16(kbase + (size_t)(kvb + krow) * (QSTR * 2) + (kcol_l ^ ((krow & 7) << 4)),
                  sKb + buf * 16384 + (w * 4 + c) * 1024);
      const int vrow = vrow_l + c * 8;
      gload_lds16(vtbase + (size_t)vrow * (S * 2) + kvb * 2 + (vcol_l ^ ((vrow & 7) << 4)),
                  sVb + buf * 16384 + (w * 4 + c) * 1024);
    }
  };

  for (int seg = 0; seg < 2; ++seg) {
    const int qtl = seg ? (15 - p) : p;
    const int qw = qtl * 128 + w * 32;  // this wave's 32 q-rows
    const int qlast = qw + 31;
    const int ntiles = (qtl + 1) * 2;
    int cur = 0;
    __syncthreads();  // prior segment's last-tile reads complete before re-staging buf 0
    stage(0, 0);
    bf16x8 qf[2][4];
#pragma unroll
    for (int rg = 0; rg < 2; ++rg) {
      const bf16* Qp = Q + (size_t)(b * S + qw + rg * 16 + lr) * QSTR + h * HD + lk * 8;
#pragma unroll
      for (int i = 0; i < 4; ++i) qf[rg][i] = *reinterpret_cast<const bf16x8*>(Qp + i * 32);
    }
    f32x4 oacc[2][8] = {};
    float mrow[2][4] = {{-3e38f, -3e38f, -3e38f, -3e38f}, {-3e38f, -3e38f, -3e38f, -3e38f}};
    float lsum[2][4] = {};
    __syncthreads();  // tile 0 resident
    for (int tt = 0; tt < ntiles; ++tt) {
      const int kvb = tt * 64;
      if (tt + 1 < ntiles) stage(kvb + 64, cur ^ 1);  // prefetch hides under compute
      const char* sKc = sKb + cur * 16384;
      const char* sVc = sVb + cur * 16384;
      if (kvb <= qlast) {  // skip fully-masked wave-tiles (stage+barrier still run)
        // ---- QK^T: 32q x 64kv ----
        float pm[2][4][4];
#pragma unroll
        for (int c = 0; c < 4; ++c) {
          f32x4 s0 = {}, s1 = {};
#pragma unroll
          for (int kf = 0; kf < 4; ++kf) {
            bf16x8 kf8 = *reinterpret_cast<const bf16x8*>(
                sKc + (c * 16 + lr) * 256 + (((kf * 64) + (lk << 4)) ^ swz));
            s0 = __builtin_amdgcn_mfma_f32_16x16x32_bf16(qf[0][kf], kf8, s0, 0, 0, 0);
            s1 = __builtin_amdgcn_mfma_f32_16x16x32_bf16(qf[1][kf], kf8, s1, 0, 0, 0);
          }
#pragma unroll
          for (int r = 0; r < 4; ++r) { pm[0][c][r] = s0[r]; pm[1][c][r] = s1[r]; }
        }
        // ---- causal mask (wave-uniform branch; near-diagonal only) ----
        if (kvb + 63 > qw) {
#pragma unroll
          for (int rg = 0; rg < 2; ++rg)
#pragma unroll
            for (int c = 0; c < 4; ++c) {
              const int col = kvb + c * 16 + lr;
#pragma unroll
              for (int r = 0; r < 4; ++r)
                if (col > qw + rg * 16 + lk * 4 + r) pm[rg][c][r] = -3e38f;
            }
        }
        // ---- defer-max online softmax ----
        float pmax[2][4];
#pragma unroll
        for (int rg = 0; rg < 2; ++rg)
#pragma unroll
          for (int r = 0; r < 4; ++r)
            pmax[rg][r] = fmaxf(fmaxf(pm[rg][0][r], pm[rg][1][r]), fmaxf(pm[rg][2][r], pm[rg][3][r]));
        bool hi = false;
#pragma unroll
        for (int rg = 0; rg < 2; ++rg)
#pragma unroll
          for (int r = 0; r < 4; ++r) hi |= (pmax[rg][r] > mrow[rg][r] + 8.f);
        if (__any(hi)) {
          float mx[2][4];
#pragma unroll
          for (int rg = 0; rg < 2; ++rg)
#pragma unroll
            for (int r = 0; r < 4; ++r) mx[rg][r] = pmax[rg][r];
#pragma unroll
          for (int off = 1; off < 16; off <<= 1)
#pragma unroll
            for (int rg = 0; rg < 2; ++rg)
#pragma unroll
              for (int r = 0; r < 4; ++r) mx[rg][r] = fmaxf(mx[rg][r], __shfl_xor(mx[rg][r], off));
#pragma unroll
          for (int rg = 0; rg < 2; ++rg)
#pragma unroll
            for (int r = 0; r < 4; ++r) {
              float mn = fmaxf(mrow[rg][r], mx[rg][r]);
              float fac = fexp2(mrow[rg][r] - mn);
              mrow[rg][r] = mn;
              lsum[rg][r] *= fac;
#pragma unroll
              for (int ch = 0; ch < 8; ++ch) oacc[rg][ch][r] *= fac;
            }
        }
#pragma unroll
        for (int rg = 0; rg < 2; ++rg) {
#pragma unroll
          for (int c = 0; c < 4; ++c)
#pragma unroll
            for (int r = 0; r < 4; ++r) pm[rg][c][r] = fexp2(pm[rg][c][r] - mrow[rg][r]);
#pragma unroll
          for (int r = 0; r < 4; ++r)
            lsum[rg][r] += (pm[rg][0][r] + pm[rg][1][r]) + (pm[rg][2][r] + pm[rg][3][r]);
        }
        // ---- P: D-frag -> A-frag via per-wave sP, reused rg=0 then rg=1 ----
        bf16x8 pf[2][2];
#pragma unroll
        for (int rg = 0; rg < 2; ++rg) {
#pragma unroll
          for (int c = 0; c < 4; ++c)
#pragma unroll
            for (int r = 0; r < 4; ++r) sP[w][lk * 4 + r][c * 16 + lr] = (bf16)pm[rg][c][r];
          pf[rg][0] = *reinterpret_cast<const bf16x8*>(&sP[w][lr][lk * 8]);
          pf[rg][1] = *reinterpret_cast<const bf16x8*>(&sP[w][lr][32 + lk * 8]);
        }
        // ---- PV: out[32q][128d] += P[32q][64kv] * V^T ----
#pragma unroll
        for (int ch = 0; ch < 8; ++ch) {
          bf16x8 vf0 = *reinterpret_cast<const bf16x8*>(
              sVc + (ch * 16 + lr) * 128 + ((lk << 4) ^ swz));
          bf16x8 vf1 = *reinterpret_cast<const bf16x8*>(
              sVc + (ch * 16 + lr) * 128 + ((64 + (lk << 4)) ^ swz));
          oacc[0][ch] = __builtin_amdgcn_mfma_f32_16x16x32_bf16(pf[0][0], vf0, oacc[0][ch], 0, 0, 0);
          oacc[0][ch] = __builtin_amdgcn_mfma_f32_16x16x32_bf16(pf[0][1], vf1, oacc[0][ch], 0, 0, 0);
          oacc[1][ch] = __builtin_amdgcn_mfma_f32_16x16x32_bf16(pf[1][0], vf0, oacc[1][ch], 0, 0, 0);
          oacc[1][ch] = __builtin_amdgcn_mfma_f32_16x16x32_bf16(pf[1][1], vf1, oacc[1][ch], 0, 0, 0);
        }
      }
      __syncthreads();  // single barrier per tile: drains prefetch, fences buffer reuse
      cur ^= 1;
    }
    // final lsum reduce, normalize, write
#pragma unroll
    for (int off = 1; off < 16; off <<= 1)
#pragma unroll
      for (int rg = 0; rg < 2; ++rg)
#pragma unroll
        for (int r = 0; r < 4; ++r) lsum[rg][r] += __shfl_xor(lsum[rg][r], off);
#pragma unroll
    for (int rg = 0; rg < 2; ++rg) {
      float inv[4];
#pragma unroll
      for (int r = 0; r < 4; ++r) inv[r] = 1.0f / lsum[rg][r];
      bf16* Op = O + (size_t)(b * S + qw + rg * 16) * OSTR + h * HD;
#pragma unroll
      for (int ch = 0; ch < 8; ++ch)
#pragma unroll
        for (int r = 0; r < 4; ++r)
          Op[(size_t)(lk * 4 + r) * OSTR + ch * 16 + lr] = (bf16)(oacc[rg][ch][r] * inv[r]);
    }
  }
}

extern "C" void kernel_launch(void* const* d_in, const int* in_sizes, int n_in,
                              void* d_out, int out_size, void* d_ws, size_t ws_size,
                              hipStream_t stream) {
  const float* hs = (const float*)d_in[0];
  // d_in[1] = attention_mask: pure causal, applied analytically
  const float* cosb = (const float*)d_in[2];
  const float* sinb = (const float*)d_in[3];
  const float* Wq = (const float*)d_in[4];
  const float* Wk = (const float*)d_in[5];
  const float* Wv = (const float*)d_in[6];
  const float* Wo = (const float*)d_in[7];
  float* out = (float*)d_out;

  constexpr int B = 2, S = 2048, H = 2048, NH = 16, NKV = 4, HD = 128;
  constexpr int T = B * S;
  constexpr size_t MB = 1024 * 1024;

  // Workspace plan (d_ws 24 MiB):
  //   d_ws[ 0:16M) : Xb (bf16 X), reused as Ob after QKV projection
  //   d_ws[16:24M) : WtQ (8MB) -> later WtO (8MB)
  //   d_out[ 0:24M): Cqkv bf16 [4096][3072] (Q | K | V)
  //   d_out[24:28M): Vt [8][128][2048]
  //   d_out[28:32M): WtKV [1024][2048]
  const size_t ws_need = 24 * MB;
  if (ws_size < ws_need) {
    k_diag<<<1, 64, 0, stream>>>(out, 1000.0f + (float)(ws_size / MB));
    return;
  }
  bf16* Xb = (bf16*)d_ws;
  bf16* WtQ = (bf16*)((char*)d_ws + 16 * MB);  // also WtO slot later
  bf16* Ob = Xb;
  bf16* Cqkv = (bf16*)d_out;
  bf16* Vtb = (bf16*)((char*)d_out + 24 * MB);
  bf16* WtKV = (bf16*)((char*)d_out + 28 * MB);

  k_cvt_bf16<<<T * H / 4 / 256, 256, 0, stream>>>(hs, Xb, T * H / 4);

  k_transpose_w<<<dim3(H / 32, H / 32), 256, 0, stream>>>(Wq, WtQ, H, H);
  k_transpose_w<<<dim3(H / 32, (NKV * HD) / 32), 256, 0, stream>>>(Wk, WtKV, H, NKV * HD);
  k_transpose_w<<<dim3(H / 32, (NKV * HD) / 32), 256, 0, stream>>>(Wv, WtKV + (size_t)(NKV * HD) * H, H, NKV * HD);

  // fused QKV projection: C[4096][3072], grid 16x12 = 192 blocks, 2D XCD supertile
  k_gemm3<bf16><<<dim3(16, 12), 512, 0, stream>>>(Xb, WtQ, WtKV, 2048, Cqkv, 3072, H);

  // V -> Vt (V gets no RoPE)
  k_transpose_v<<<dim3(S / 32, HD / 32, B * NKV), 256, 0, stream>>>(Cqkv, Vtb);

  // RoPE; Q folds log2(e)/sqrt(HD) so QK^T lands in log2 domain
  const float qscale = 0.12751743f;  // log2(e) / sqrt(128)
  k_rope<<<(T * NH * 64) / 256, 256, 0, stream>>>(Cqkv, cosb, sinb, NH, 3072, qscale, T * NH * 64);
  k_rope<<<(T * NKV * 64) / 256, 256, 0, stream>>>(Cqkv + 2048, cosb, sinb, NKV, 3072, 1.0f, T * NKV * 64);

  // Attention: reads Q/K (Cqkv) + Vt, writes Ob into d_ws (Xb dead)
  k_attn<<<256, 256, 0, stream>>>(Cqkv, Cqkv + 2048, Vtb, Ob);

  // O projection: reads only d_ws (Ob, WtO), writes all of d_out; full 256-block fill
  k_transpose_w<<<dim3(H / 32, H / 32), 256, 0, stream>>>(Wo, WtQ, H, H);
  k_gemm2<256, float><<<dim3(16, 16), 512, 0, stream>>>(Ob, WtQ, out, H, H);
}

// Round 12
// 224.916 us; speedup vs baseline: 1.2496x; 1.0413x over previous
//
#include <hip/hip_runtime.h>
#include <hip/hip_bf16.h>

typedef __bf16 bf16;
typedef __bf16 bf16x4 __attribute__((ext_vector_type(4)));
typedef __bf16 bf16x8 __attribute__((ext_vector_type(8)));
typedef float f32x4 __attribute__((ext_vector_type(4)));

__device__ __forceinline__ void gload_lds16(const void* g, void* l) {
  __builtin_amdgcn_global_load_lds((__attribute__((address_space(1))) void*)(g),
                                   (__attribute__((address_space(3))) void*)(l), 16, 0, 0);
}
// raw 2^x (v_exp_f32 IS exp2)
__device__ __forceinline__ float fexp2(float x) {
  float r;
  asm volatile("v_exp_f32 %0, %1" : "=v"(r) : "v"(x));
  return r;
}
#define S_WAITCNT_VM(n) asm volatile("s_waitcnt vmcnt(" #n ")" ::: "memory")

// ---------------- diagnostic: encode ws_size into output if workspace too small ----
__global__ void k_diag(float* __restrict__ o, float v) { o[threadIdx.x] = v; }

// ---------------- fp32 -> bf16 convert (vectorized) ----------------
__global__ void k_cvt_bf16(const float* __restrict__ x, bf16* __restrict__ y, int n4) {
  int i = blockIdx.x * blockDim.x + threadIdx.x;
  if (i < n4) {
    float4 v = reinterpret_cast<const float4*>(x)[i];
    bf16x4 o = {(bf16)v.x, (bf16)v.y, (bf16)v.z, (bf16)v.w};
    reinterpret_cast<bf16x4*>(y)[i] = o;
  }
}

// ---------------- W (K x N fp32, row-major) -> Wt (N x K bf16) ----------------
__global__ void k_transpose_w(const float* __restrict__ W, bf16* __restrict__ Wt, int K, int N) {
  __shared__ float tile[32][33];
  int kb = blockIdx.x * 32, nb = blockIdx.y * 32;
  int tx = threadIdx.x & 31, ty = threadIdx.x >> 5;
#pragma unroll
  for (int i = 0; i < 32; i += 8)
    tile[ty + i][tx] = W[(size_t)(kb + ty + i) * N + nb + tx];
  __syncthreads();
#pragma unroll
  for (int i = 0; i < 32; i += 8)
    Wt[(size_t)(nb + ty + i) * K + kb + tx] = (bf16)tile[tx][ty + i];
}

// ---------------- V (cols 2560.. of Cqkv, stride 3072) -> Vt[b][kvh][HD][S] ----------------
__global__ void k_transpose_v(const bf16* __restrict__ Cq, bf16* __restrict__ Vt) {
  __shared__ bf16 tile[32][34];
  constexpr int S = 2048, CSTR = 3072;
  int sb = blockIdx.x * 32, db = blockIdx.y * 32, bh = blockIdx.z;  // bh = b*4+kvh
  int b = bh >> 2, kvh = bh & 3;
  int tx = threadIdx.x & 31, ty = threadIdx.x >> 5;
  const bf16* src = Cq + (size_t)b * S * CSTR + 2560 + kvh * 128;
#pragma unroll
  for (int i = 0; i < 32; i += 8)
    tile[ty + i][tx] = src[(size_t)(sb + ty + i) * CSTR + db + tx];
  __syncthreads();
  bf16* dst = Vt + (size_t)bh * 128 * S;
#pragma unroll
  for (int i = 0; i < 32; i += 8)
    dst[(size_t)(db + ty + i) * S + sb + tx] = tile[tx][ty + i];
}

// ---------------- 256x256 bf16 GEMM, 4-phase counted-vmcnt, 2D XCD supertile ----------
template <typename OT>
__global__ __launch_bounds__(512) void k_gemm3(const bf16* __restrict__ A,
                                               const bf16* __restrict__ B0,
                                               const bf16* __restrict__ B1, int nsplit,
                                               OT* __restrict__ C, int Ncols, int Kd) {
  __shared__ __align__(16) bf16 lds_[65536];  // 128 KiB
  char* lds = (char*)lds_;
  const int t = threadIdx.x, w = t >> 6, l = t & 63;
  const int lr = l & 15, lk = l >> 4;
  const int gx = gridDim.x;
  const int flat = blockIdx.y * gx + blockIdx.x;
  const int xcd = flat & 7, local = flat >> 3;
  const int mi = (xcd & 3) * (gx >> 2) + (local & ((gx >> 2) - 1));
  const int ni = (xcd >> 2) * (gridDim.y >> 1) + (local >> 2);
  const int m0 = mi * 256, n0 = ni * 256;
  const int wm = w >> 2, wn = w & 3;
  const bf16* Bt = (n0 < nsplit) ? B0 + (size_t)n0 * Kd : B1 + (size_t)(n0 - nsplit) * Kd;
  const int nkt = Kd >> 6;
  const int srow = l >> 2;
  const int lch = (l & 3) ^ ((srow + (srow >> 2)) & 3);
  auto stA = [&](int tile, int unit) {
    if (tile >= nkt) return;
    const bf16* s = A + (size_t)(m0 + unit * 64 + (w >> 1) * 16 + srow) * Kd +
                    (tile << 6) + (w & 1) * 32 + lch * 8;
    gload_lds16(s, lds + (tile & 1) * 32768 + unit * 8192 + w * 1024);
  };
  auto stB = [&](int tile, int grp) {
    if (tile >= nkt) return;
    const bf16* s = Bt + (size_t)((w >> 1) * 64 + grp * 16 + srow) * Kd +
                    (tile << 6) + (w & 1) * 32 + lch * 8;
    gload_lds16(s, lds + 65536 + (tile & 1) * 32768 + grp * 8192 + w * 1024);
  };
  const int rdoff = lr * 64 + ((lk ^ ((lr + (lr >> 2)) & 3)) << 4);

  f32x4 acc[8][4] = {};
  stA(0, 0); stA(0, 1); stA(0, 2); stA(0, 3);
  stB(0, 0);
  stA(1, 0); stB(0, 1); stA(1, 1); stB(0, 2); stA(1, 2); stB(0, 3);

  for (int kt = 0; kt < nkt; ++kt) {
    const int buf = kt & 1;
    const char* Ab = lds + buf * 32768;
    const char* Bb = lds + 65536 + buf * 32768;
    bf16x8 af[8][2];
#pragma unroll
    for (int p = 0; p < 4; ++p) {
      if (kt + 1 < nkt) { S_WAITCNT_VM(6); } else { S_WAITCNT_VM(0); }
      __builtin_amdgcn_sched_barrier(0);
      __builtin_amdgcn_s_barrier();
      __builtin_amdgcn_sched_barrier(0);
      if (p == 0) stA(kt + 1, 3); else stA(kt + 2, p - 1);
      stB(kt + 1, p);
      if (p == 0) {
#pragma unroll
        for (int i = 0; i < 8; ++i) {
          const char* ub = Ab + (wm * 2 + (i >> 2)) * 8192 + (i & 3) * 2048;
          af[i][0] = *reinterpret_cast<const bf16x8*>(ub + rdoff);
          af[i][1] = *reinterpret_cast<const bf16x8*>(ub + 1024 + rdoff);
        }
      }
      bf16x8 b0 = *reinterpret_cast<const bf16x8*>(Bb + p * 8192 + wn * 2048 + rdoff);
      bf16x8 b1 = *reinterpret_cast<const bf16x8*>(Bb + p * 8192 + wn * 2048 + 1024 + rdoff);
      __builtin_amdgcn_s_setprio(1);
#pragma unroll
      for (int i = 0; i < 8; ++i) {
        acc[i][p] = __builtin_amdgcn_mfma_f32_16x16x32_bf16(af[i][0], b0, acc[i][p], 0, 0, 0);
        acc[i][p] = __builtin_amdgcn_mfma_f32_16x16x32_bf16(af[i][1], b1, acc[i][p], 0, 0, 0);
      }
      __builtin_amdgcn_s_setprio(0);
      __builtin_amdgcn_sched_barrier(0);
    }
  }
#pragma unroll
  for (int i = 0; i < 8; ++i)
#pragma unroll
    for (int j = 0; j < 4; ++j)
#pragma unroll
      for (int r = 0; r < 4; ++r) {
        int row = m0 + wm * 128 + i * 16 + lk * 4 + r;
        int col = n0 + wn * 64 + j * 16 + lr;
        if constexpr (sizeof(OT) == 4)
          C[(size_t)row * Ncols + col] = acc[i][j][r];
        else
          C[(size_t)row * Ncols + col] = (bf16)acc[i][j][r];
      }
}

// ---------------- 2-phase GEMM (round-6 verified) for O projection ------
template <int BM, typename OT>
__global__ __launch_bounds__(512) void k_gemm2(const bf16* __restrict__ A, const bf16* __restrict__ Bt,
                                               OT* __restrict__ C, int N, int Kd) {
  constexpr int NA = (BM / 16) * 2;
  constexpr int NB = 16;
  constexpr int NST = NA + NB;
  constexpr int NSW = NST / 8;
  constexpr int WM = BM / 4;
  constexpr int RG = WM / 16;
  __shared__ __align__(16) bf16 sAB[2][NST * 512];
  const int t = threadIdx.x, w = t >> 6, l = t & 63;
  const int lr = l & 15, lk = l >> 4;
  const int gx = gridDim.x;
  const int nwg = gx * gridDim.y;
  const int flat = blockIdx.y * gx + blockIdx.x;
  const int vid = (flat & 7) * (nwg >> 3) + (flat >> 3);
  const int m0 = (vid % gx) * BM, n0 = (vid / gx) * 128;
  const int wm = w >> 1, wn = w & 1;
  const int srow = l >> 2;
  const int lchunk = (l & 3) ^ (((l >> 5) & 1) << 1);
  const int rdoff = lr * 64 + ((lk * 16) ^ ((lr >> 3) << 5));
  const int nkt = Kd >> 6;
  char* lds = (char*)sAB;

  auto stage = [&](int kt, int buf) {
    const int k0 = kt << 6;
#pragma unroll
    for (int u = 0; u < NSW; ++u) {
      const int s = w * NSW + u;
      const bf16* src;
      if (s < NA)
        src = A + (size_t)(m0 + (s >> 1) * 16 + srow) * Kd + k0 + (s & 1) * 32 + lchunk * 8;
      else
        src = Bt + (size_t)(n0 + ((s - NA) >> 1) * 16 + srow) * Kd + k0 + ((s - NA) & 1) * 32 + lchunk * 8;
      gload_lds16(src, lds + buf * (NST * 1024) + s * 1024);
    }
  };

  f32x4 acc[RG][4] = {};
  stage(0, 0);
  stage(1, 1);
  if constexpr (NSW == 6) S_WAITCNT_VM(6); else S_WAITCNT_VM(4);
  __builtin_amdgcn_s_barrier();
  int c = 0;
  for (int kt = 0; kt < nkt; ++kt) {
    __builtin_amdgcn_sched_barrier(0);
    const char* base = lds + c * (NST * 1024);
    bf16x8 af[RG][2], bfr[4][2];
#pragma unroll
    for (int i = 0; i < RG; ++i)
#pragma unroll
      for (int kk = 0; kk < 2; ++kk)
        af[i][kk] = *reinterpret_cast<const bf16x8*>(base + ((wm * RG + i) * 2 + kk) * 1024 + rdoff);
#pragma unroll
    for (int j = 0; j < 4; ++j)
#pragma unroll
      for (int kk = 0; kk < 2; ++kk)
        bfr[j][kk] = *reinterpret_cast<const bf16x8*>(base + (NA + (wn * 4 + j) * 2 + kk) * 1024 + rdoff);
    __builtin_amdgcn_s_setprio(1);
#pragma unroll
    for (int i = 0; i < RG; ++i)
#pragma unroll
      for (int j = 0; j < 4; ++j) {
        acc[i][j] = __builtin_amdgcn_mfma_f32_16x16x32_bf16(af[i][0], bfr[j][0], acc[i][j], 0, 0, 0);
        acc[i][j] = __builtin_amdgcn_mfma_f32_16x16x32_bf16(af[i][1], bfr[j][1], acc[i][j], 0, 0, 0);
      }
    __builtin_amdgcn_s_setprio(0);
    __builtin_amdgcn_sched_barrier(0);
    asm volatile("" ::: "memory");
    __builtin_amdgcn_s_barrier();
    if (kt + 2 < nkt) stage(kt + 2, c);
    if (kt + 1 < nkt) {
      if (kt + 2 < nkt) {
        if constexpr (NSW == 6) S_WAITCNT_VM(6); else S_WAITCNT_VM(4);
      } else {
        S_WAITCNT_VM(0);
      }
      asm volatile("" ::: "memory");
      __builtin_amdgcn_s_barrier();
    }
    c ^= 1;
  }
#pragma unroll
  for (int i = 0; i < RG; ++i)
#pragma unroll
    for (int j = 0; j < 4; ++j)
#pragma unroll
      for (int r = 0; r < 4; ++r) {
        int row = m0 + wm * WM + i * 16 + lk * 4 + r;
        int col = n0 + wn * 64 + j * 16 + lr;
        if constexpr (sizeof(OT) == 4)
          C[(size_t)row * N + col] = acc[i][j][r];
        else
          C[(size_t)row * N + col] = (bf16)acc[i][j][r];
      }
}

// ---------------- RoPE in place (optionally folds score scale into Q) ----------------
__global__ void k_rope(bf16* __restrict__ X, const float* __restrict__ cs, const float* __restrict__ sn,
                       int nh, int rowstride, float scale, int total) {
  int idx = blockIdx.x * blockDim.x + threadIdx.x;
  if (idx >= total) return;
  int d = idx & 63;
  int th = idx >> 6;
  int h = th % nh;
  int tok = th / nh;
  size_t base = (size_t)tok * rowstride + h * 128;
  float c = cs[tok * 128 + d], s = sn[tok * 128 + d];
  float x1 = (float)X[base + d];
  float x2 = (float)X[base + d + 64];
  X[base + d] = (bf16)((x1 * c - x2 * s) * scale);
  X[base + d + 64] = (bf16)((x2 * c + x1 * s) * scale);
}

// ---------------- causal flash attention: 8 waves = 4 q-groups x 2 kv-halves ----------
// Block = 512 thr; wq = w&3 owns 32 q-rows, wk = w>>2 owns one 32-kv half of each
// 64-kv tile. Paired segments {p, 15-p} -> uniform 34 tiles/block; grid 256 (1/CU),
// 8 waves/CU = 2 waves/SIMD (fixes round-11's 1/SIMD latency exposure while keeping
// its halved DS traffic). Each kv-half wave keeps independent flash partials; one
// LDS merge per segment (oacc reuses dead K/V region, m/l over dead sP; wk=0 writes O).
// Numeric guard: mask = -1e38, m-init = -1e30 (masked-only waves: exp2(-1e38+1e30)=0,
// never exp2(0)=1). K/V double-buffered, prefetch before compute, 1 barrier/tile.
__global__ __launch_bounds__(512) void k_attn(const bf16* __restrict__ Q, const bf16* __restrict__ KV,
                                              const bf16* __restrict__ Vt, bf16* __restrict__ O) {
  constexpr int S = 2048, HD = 128, QSTR = 3072, OSTR = 2048;
  // [0,32K): K dbuf | [32K,64K): V dbuf | [64K,74K): sP | merge: oacc@[0,64K), ml@[64K,80K)
  __shared__ __align__(16) char smem[81920];
  const int bid = blockIdx.x;
  const int vid = (bid & 7) * 32 + (bid >> 3);  // XCD swizzle: one (b,kvh) per XCD
  const int p = vid & 7, bh = vid >> 3;
  const int h = bh & 15, b = bh >> 4;
  const int t = threadIdx.x, w = t >> 6, l = t & 63;
  const int wq = w & 3, wk = w >> 2;
  const int lr = l & 15, lk = l >> 4;
  const int kvh = h >> 2;
  const int swz = (lr & 7) << 4;

  const char* kbase = (const char*)(KV + (size_t)b * S * QSTR + kvh * HD);
  const int krow_l = w * 8 + (l >> 4);
  const int kcol_l = (l & 15) << 4;
  const char* vtbase = (const char*)(Vt + (size_t)(b * 4 + kvh) * HD * S);
  const int vrow_l = w * 16 + (l >> 3);
  const int vcol_l = (l & 7) << 4;
  auto stage = [&](int kvb, int buf) {
#pragma unroll
    for (int c = 0; c < 2; ++c) {
      const int krow = krow_l + c * 4;
      gload_lds16(kbase + (size_t)(kvb + krow) * (QSTR * 2) + (kcol_l ^ ((krow & 7) << 4)),
                  smem + buf * 16384 + (w * 2 + c) * 1024);
      const int vrow = vrow_l + c * 8;
      gload_lds16(vtbase + (size_t)vrow * (S * 2) + kvb * 2 + (vcol_l ^ ((vrow & 7) << 4)),
                  smem + 32768 + buf * 16384 + (w * 2 + c) * 1024);
    }
  };
  char* sPb = smem + 65536 + w * 1280;  // per-wave [16 rows][40 cols] bf16 (80B rows)

  for (int seg = 0; seg < 2; ++seg) {
    const int qtl = seg ? (15 - p) : p;
    const int qw = qtl * 128 + wq * 32;  // this wave's 32 q-rows
    const int qlast = qw + 31;
    const int ntiles = (qtl + 1) * 2;
    int cur = 0;
    __syncthreads();  // prior segment's merge reads / last-tile reads complete
    stage(0, 0);
    bf16x8 qf[2][4];
#pragma unroll
    for (int rg = 0; rg < 2; ++rg) {
      const bf16* Qp = Q + (size_t)(b * S + qw + rg * 16 + lr) * QSTR + h * HD + lk * 8;
#pragma unroll
      for (int i = 0; i < 4; ++i) qf[rg][i] = *reinterpret_cast<const bf16x8*>(Qp + i * 32);
    }
    f32x4 oacc[2][8] = {};
    float mrow[2][4] = {{-1e30f, -1e30f, -1e30f, -1e30f}, {-1e30f, -1e30f, -1e30f, -1e30f}};
    float lsum[2][4] = {};
    __syncthreads();  // tile 0 resident
    for (int tt = 0; tt < ntiles; ++tt) {
      const int kvb = tt * 64;
      if (tt + 1 < ntiles) stage(kvb + 64, cur ^ 1);  // prefetch hides under compute
      const char* sKc = smem + cur * 16384;
      const char* sVc = smem + 32768 + cur * 16384;
      const int col0 = kvb + wk * 32;  // this wave's kv-half start
      if (col0 <= qlast) {  // skip fully-masked halves (stage+barrier still run)
        // ---- QK^T: 32q x 32kv (this wave's half) ----
        float pm[2][2][4];
#pragma unroll
        for (int c = 0; c < 2; ++c) {
          f32x4 s0 = {}, s1 = {};
#pragma unroll
          for (int kf = 0; kf < 4; ++kf) {
            bf16x8 kf8 = *reinterpret_cast<const bf16x8*>(
                sKc + (wk * 32 + c * 16 + lr) * 256 + (((kf * 64) + (lk << 4)) ^ swz));
            s0 = __builtin_amdgcn_mfma_f32_16x16x32_bf16(qf[0][kf], kf8, s0, 0, 0, 0);
            s1 = __builtin_amdgcn_mfma_f32_16x16x32_bf16(qf[1][kf], kf8, s1, 0, 0, 0);
          }
#pragma unroll
          for (int r = 0; r < 4; ++r) { pm[0][c][r] = s0[r]; pm[1][c][r] = s1[r]; }
        }
        // ---- causal mask (near-diagonal only) ----
        if (col0 + 31 > qw) {
#pragma unroll
          for (int rg = 0; rg < 2; ++rg)
#pragma unroll
            for (int c = 0; c < 2; ++c) {
              const int col = col0 + c * 16 + lr;
#pragma unroll
              for (int r = 0; r < 4; ++r)
                if (col > qw + rg * 16 + lk * 4 + r) pm[rg][c][r] = -1e38f;
            }
        }
        // ---- defer-max online softmax (per kv-half partials) ----
        float pmax[2][4];
#pragma unroll
        for (int rg = 0; rg < 2; ++rg)
#pragma unroll
          for (int r = 0; r < 4; ++r) pmax[rg][r] = fmaxf(pm[rg][0][r], pm[rg][1][r]);
        bool hi = false;
#pragma unroll
        for (int rg = 0; rg < 2; ++rg)
#pragma unroll
          for (int r = 0; r < 4; ++r) hi |= (pmax[rg][r] > mrow[rg][r] + 8.f);
        if (__any(hi)) {
          float mx[2][4];
#pragma unroll
          for (int rg = 0; rg < 2; ++rg)
#pragma unroll
            for (int r = 0; r < 4; ++r) mx[rg][r] = pmax[rg][r];
#pragma unroll
          for (int off = 1; off < 16; off <<= 1)
#pragma unroll
            for (int rg = 0; rg < 2; ++rg)
#pragma unroll
              for (int r = 0; r < 4; ++r) mx[rg][r] = fmaxf(mx[rg][r], __shfl_xor(mx[rg][r], off));
#pragma unroll
          for (int rg = 0; rg < 2; ++rg)
#pragma unroll
            for (int r = 0; r < 4; ++r) {
              float mn = fmaxf(mrow[rg][r], mx[rg][r]);
              float fac = fexp2(mrow[rg][r] - mn);
              mrow[rg][r] = mn;
              lsum[rg][r] *= fac;
#pragma unroll
              for (int ch = 0; ch < 8; ++ch) oacc[rg][ch][r] *= fac;
            }
        }
#pragma unroll
        for (int rg = 0; rg < 2; ++rg) {
#pragma unroll
          for (int c = 0; c < 2; ++c)
#pragma unroll
            for (int r = 0; r < 4; ++r) pm[rg][c][r] = fexp2(pm[rg][c][r] - mrow[rg][r]);
#pragma unroll
          for (int r = 0; r < 4; ++r) lsum[rg][r] += pm[rg][0][r] + pm[rg][1][r];
        }
        // ---- P: D-frag -> A-frag via per-wave sP (16x32, reused rg0 then rg1) ----
        bf16x8 pf[2];
#pragma unroll
        for (int rg = 0; rg < 2; ++rg) {
#pragma unroll
          for (int c = 0; c < 2; ++c)
#pragma unroll
            for (int r = 0; r < 4; ++r)
              *(bf16*)(sPb + (lk * 4 + r) * 80 + (c * 16 + lr) * 2) = (bf16)pm[rg][c][r];
          pf[rg] = *reinterpret_cast<const bf16x8*>(sPb + lr * 80 + lk * 16);
        }
        // ---- PV: out[32q][128d] += P[32q][32kv] * V^T(half) ----
#pragma unroll
        for (int ch = 0; ch < 8; ++ch) {
          bf16x8 vf = *reinterpret_cast<const bf16x8*>(
              sVc + (ch * 16 + lr) * 128 + ((wk * 64 + (lk << 4)) ^ swz));
          oacc[0][ch] = __builtin_amdgcn_mfma_f32_16x16x32_bf16(pf[0], vf, oacc[0][ch], 0, 0, 0);
          oacc[1][ch] = __builtin_amdgcn_mfma_f32_16x16x32_bf16(pf[1], vf, oacc[1][ch], 0, 0, 0);
        }
      }
      __syncthreads();  // single barrier per tile
      cur ^= 1;
    }
    // ---- in-wave lsum reduce over lr (kv direction) ----
#pragma unroll
    for (int off = 1; off < 16; off <<= 1)
#pragma unroll
      for (int rg = 0; rg < 2; ++rg)
#pragma unroll
        for (int r = 0; r < 4; ++r) lsum[rg][r] += __shfl_xor(lsum[rg][r], off);
    // ---- cross-half merge: wk=1 publishes partials; wk=0 merges + writes O ----
    float* ob = (float*)smem;            // 64KB (dead K/V region)
    float* mlb = (float*)(smem + 65536); // 16KB (dead sP region + tail)
    if (wk == 1) {
#pragma unroll
      for (int rg = 0; rg < 2; ++rg) {
#pragma unroll
        for (int ch = 0; ch < 8; ++ch)
          *reinterpret_cast<f32x4*>(&ob[wq * 4096 + l * 64 + (rg * 8 + ch) * 4]) = oacc[rg][ch];
#pragma unroll
        for (int r = 0; r < 4; ++r) {
          mlb[wq * 1024 + l * 16 + rg * 8 + r] = mrow[rg][r];
          mlb[wq * 1024 + l * 16 + rg * 8 + 4 + r] = lsum[rg][r];
        }
      }
    }
    __syncthreads();
    if (wk == 0) {
      float sc0[2][4], sc1[2][4];
#pragma unroll
      for (int rg = 0; rg < 2; ++rg)
#pragma unroll
        for (int r = 0; r < 4; ++r) {
          float m1 = mlb[wq * 1024 + l * 16 + rg * 8 + r];
          float l1 = mlb[wq * 1024 + l * 16 + rg * 8 + 4 + r];
          float m = fmaxf(mrow[rg][r], m1);
          float w0 = fexp2(mrow[rg][r] - m), w1 = fexp2(m1 - m);
          float inv = 1.0f / (lsum[rg][r] * w0 + l1 * w1);
          sc0[rg][r] = w0 * inv;
          sc1[rg][r] = w1 * inv;
        }
#pragma unroll
      for (int rg = 0; rg < 2; ++rg) {
        bf16* Op = O + (size_t)(b * S + qw + rg * 16) * OSTR + h * HD;
#pragma unroll
        for (int ch = 0; ch < 8; ++ch) {
          f32x4 o1 = *reinterpret_cast<const f32x4*>(&ob[wq * 4096 + l * 64 + (rg * 8 + ch) * 4]);
#pragma unroll
          for (int r = 0; r < 4; ++r)
            Op[(size_t)(lk * 4 + r) * OSTR + ch * 16 + lr] =
                (bf16)(oacc[rg][ch][r] * sc0[rg][r] + o1[r] * sc1[rg][r]);
        }
      }
    }
  }
}

extern "C" void kernel_launch(void* const* d_in, const int* in_sizes, int n_in,
                              void* d_out, int out_size, void* d_ws, size_t ws_size,
                              hipStream_t stream) {
  const float* hs = (const float*)d_in[0];
  // d_in[1] = attention_mask: pure causal, applied analytically
  const float* cosb = (const float*)d_in[2];
  const float* sinb = (const float*)d_in[3];
  const float* Wq = (const float*)d_in[4];
  const float* Wk = (const float*)d_in[5];
  const float* Wv = (const float*)d_in[6];
  const float* Wo = (const float*)d_in[7];
  float* out = (float*)d_out;

  constexpr int B = 2, S = 2048, H = 2048, NH = 16, NKV = 4, HD = 128;
  constexpr int T = B * S;
  constexpr size_t MB = 1024 * 1024;

  // Workspace plan (d_ws 24 MiB):
  //   d_ws[ 0:16M) : Xb (bf16 X), reused as Ob after QKV projection
  //   d_ws[16:24M) : WtQ (8MB) -> later WtO (8MB)
  //   d_out[ 0:24M): Cqkv bf16 [4096][3072] (Q | K | V)
  //   d_out[24:28M): Vt [8][128][2048]
  //   d_out[28:32M): WtKV [1024][2048]
  const size_t ws_need = 24 * MB;
  if (ws_size < ws_need) {
    k_diag<<<1, 64, 0, stream>>>(out, 1000.0f + (float)(ws_size / MB));
    return;
  }
  bf16* Xb = (bf16*)d_ws;
  bf16* WtQ = (bf16*)((char*)d_ws + 16 * MB);  // also WtO slot later
  bf16* Ob = Xb;
  bf16* Cqkv = (bf16*)d_out;
  bf16* Vtb = (bf16*)((char*)d_out + 24 * MB);
  bf16* WtKV = (bf16*)((char*)d_out + 28 * MB);

  k_cvt_bf16<<<T * H / 4 / 256, 256, 0, stream>>>(hs, Xb, T * H / 4);

  k_transpose_w<<<dim3(H / 32, H / 32), 256, 0, stream>>>(Wq, WtQ, H, H);
  k_transpose_w<<<dim3(H / 32, (NKV * HD) / 32), 256, 0, stream>>>(Wk, WtKV, H, NKV * HD);
  k_transpose_w<<<dim3(H / 32, (NKV * HD) / 32), 256, 0, stream>>>(Wv, WtKV + (size_t)(NKV * HD) * H, H, NKV * HD);

  // fused QKV projection: C[4096][3072], grid 16x12 = 192 blocks, 2D XCD supertile
  k_gemm3<bf16><<<dim3(16, 12), 512, 0, stream>>>(Xb, WtQ, WtKV, 2048, Cqkv, 3072, H);

  // V -> Vt (V gets no RoPE)
  k_transpose_v<<<dim3(S / 32, HD / 32, B * NKV), 256, 0, stream>>>(Cqkv, Vtb);

  // RoPE; Q folds log2(e)/sqrt(HD) so QK^T lands in log2 domain
  const float qscale = 0.12751743f;  // log2(e) / sqrt(128)
  k_rope<<<(T * NH * 64) / 256, 256, 0, stream>>>(Cqkv, cosb, sinb, NH, 3072, qscale, T * NH * 64);
  k_rope<<<(T * NKV * 64) / 256, 256, 0, stream>>>(Cqkv + 2048, cosb, sinb, NKV, 3072, 1.0f, T * NKV * 64);

  // Attention: 256 blocks x 512 threads (8 waves: 4 q-groups x 2 kv-halves)
  k_attn<<<256, 512, 0, stream>>>(Cqkv, Cqkv + 2048, Vtb, Ob);

  // O projection: reads only d_ws (Ob, WtO), writes all of d_out; full 256-block fill
  k_transpose_w<<<dim3(H / 32, H / 32), 256, 0, stream>>>(Wo, WtQ, H, H);
  k_gemm2<256, float><<<dim3(16, 16), 512, 0, stream>>>(Ob, WtQ, out, H, H);
}

// Round 13
// 213.284 us; speedup vs baseline: 1.3178x; 1.0545x over previous
//
#include <hip/hip_runtime.h>
#include <hip/hip_bf16.h>

typedef __bf16 bf16;
typedef __bf16 bf16x4 __attribute__((ext_vector_type(4)));
typedef __bf16 bf16x8 __attribute__((ext_vector_type(8)));
typedef float f32x4 __attribute__((ext_vector_type(4)));

__device__ __forceinline__ void gload_lds16(const void* g, void* l) {
  __builtin_amdgcn_global_load_lds((__attribute__((address_space(1))) void*)(g),
                                   (__attribute__((address_space(3))) void*)(l), 16, 0, 0);
}
// raw 2^x (v_exp_f32 IS exp2)
__device__ __forceinline__ float fexp2(float x) {
  float r;
  asm volatile("v_exp_f32 %0, %1" : "=v"(r) : "v"(x));
  return r;
}
#define S_WAITCNT_VM(n) asm volatile("s_waitcnt vmcnt(" #n ")" ::: "memory")
#define LDS_FENCE() asm volatile("" ::: "memory")

// ---------------- diagnostic: encode ws_size into output if workspace too small ----
__global__ void k_diag(float* __restrict__ o, float v) { o[threadIdx.x] = v; }

// ---------------- fp32 -> bf16 convert (vectorized) ----------------
__global__ void k_cvt_bf16(const float* __restrict__ x, bf16* __restrict__ y, int n4) {
  int i = blockIdx.x * blockDim.x + threadIdx.x;
  if (i < n4) {
    float4 v = reinterpret_cast<const float4*>(x)[i];
    bf16x4 o = {(bf16)v.x, (bf16)v.y, (bf16)v.z, (bf16)v.w};
    reinterpret_cast<bf16x4*>(y)[i] = o;
  }
}

// ---------------- W (K x N fp32, row-major) -> Wt (N x K bf16) ----------------
__global__ void k_transpose_w(const float* __restrict__ W, bf16* __restrict__ Wt, int K, int N) {
  __shared__ float tile[32][33];
  int kb = blockIdx.x * 32, nb = blockIdx.y * 32;
  int tx = threadIdx.x & 31, ty = threadIdx.x >> 5;
#pragma unroll
  for (int i = 0; i < 32; i += 8)
    tile[ty + i][tx] = W[(size_t)(kb + ty + i) * N + nb + tx];
  __syncthreads();
#pragma unroll
  for (int i = 0; i < 32; i += 8)
    Wt[(size_t)(nb + ty + i) * K + kb + tx] = (bf16)tile[tx][ty + i];
}

// ---------------- V (cols 2560.. of Cqkv, stride 3072) -> Vt[b][kvh][HD][S] ----------------
__global__ void k_transpose_v(const bf16* __restrict__ Cq, bf16* __restrict__ Vt) {
  __shared__ bf16 tile[32][34];
  constexpr int S = 2048, CSTR = 3072;
  int sb = blockIdx.x * 32, db = blockIdx.y * 32, bh = blockIdx.z;  // bh = b*4+kvh
  int b = bh >> 2, kvh = bh & 3;
  int tx = threadIdx.x & 31, ty = threadIdx.x >> 5;
  const bf16* src = Cq + (size_t)b * S * CSTR + 2560 + kvh * 128;
#pragma unroll
  for (int i = 0; i < 32; i += 8)
    tile[ty + i][tx] = src[(size_t)(sb + ty + i) * CSTR + db + tx];
  __syncthreads();
  bf16* dst = Vt + (size_t)bh * 128 * S;
#pragma unroll
  for (int i = 0; i < 32; i += 8)
    dst[(size_t)(db + ty + i) * S + sb + tx] = tile[tx][ty + i];
}

// ---------------- k_gemm4: 256x256, m201-faithful 4-phase K-loop ----------------
// C[M,N] = A[M,K] * Bt[N,K]^T (Bt split at n=nsplit). 8 waves (2M x 4N), wave tile
// 128x64, acc[8][4]. LDS 128KB: A 2buf x 32KB @0, B 2buf x 32KB @64K; rows of 128B,
// 16B-chunk swizzle c ^= row&7 (bank-even), linear dest + inverse-swz global source.
// Per K-tile 4 phases (kk,h): {[vmcnt(0) @p0] barrier; stage 2 gloads(kt+1);
// ds_read af[4] (+bfr[4] @h0, reused @h1); setprio(1); 16 MFMA; setprio(0)}.
// No sched_barrier (m141 lesson); one vmcnt per K-tile; compiler handles lgkm.
template <typename OT>
__global__ __launch_bounds__(512) void k_gemm4(const bf16* __restrict__ A,
                                               const bf16* __restrict__ B0,
                                               const bf16* __restrict__ B1, int nsplit,
                                               OT* __restrict__ C, int Ncols, int Kd) {
  __shared__ __align__(16) char lds[131072];
  const int t = threadIdx.x, w = t >> 6, l = t & 63;
  const int lr = l & 15, lk = l >> 4;
  const int gx = gridDim.x;
  const int flat = blockIdx.y * gx + blockIdx.x;
  // 2D XCD supertile (round-12 verified: FETCH 73.8 -> 41MB)
  const int xcd = flat & 7, local = flat >> 3;
  const int mi = (xcd & 3) * (gx >> 2) + (local & ((gx >> 2) - 1));
  const int ni = (xcd >> 2) * (gridDim.y >> 1) + (local >> 2);
  const int m0 = mi * 256, n0 = ni * 256;
  const int wm = w >> 2, wn = w & 3;
  const bf16* Bt = (n0 < nsplit) ? B0 + (size_t)n0 * Kd : B1 + (size_t)(n0 - nsplit) * Kd;
  const int nkt = Kd >> 6;
  // staging: wave w stages rows [w*32, w*32+32) of A and B as 4 gloads each (8 rows/gload)
  const int srow8 = l >> 3;   // row within 8-row group
  const int sk = ((l & 7) ^ srow8) * 8;  // inverse-swizzled global k-chunk (elements)
  auto stA = [&](int kt, int g) {
    if (kt >= nkt) return;
    const bf16* s = A + (size_t)(m0 + w * 32 + g * 8 + srow8) * Kd + (kt << 6) + sk;
    gload_lds16(s, lds + (kt & 1) * 32768 + (w * 32 + g * 8) * 128);
  };
  auto stB = [&](int kt, int g) {
    if (kt >= nkt) return;
    const bf16* s = Bt + (size_t)(w * 32 + g * 8 + srow8) * Kd + (kt << 6) + sk;
    gload_lds16(s, lds + 65536 + (kt & 1) * 32768 + (w * 32 + g * 8) * 128);
  };

  f32x4 acc[8][4] = {};
  // prologue: tile 0 fully staged (8 gloads/wave)
#pragma unroll
  for (int g = 0; g < 4; ++g) { stA(0, g); stB(0, g); }

  for (int kt = 0; kt < nkt; ++kt) {
    const char* Ab = lds + (kt & 1) * 32768;
    const char* Bb = lds + 65536 + (kt & 1) * 32768;
    bf16x8 bfr[4];
#pragma unroll
    for (int kk = 0; kk < 2; ++kk) {
#pragma unroll
      for (int h = 0; h < 2; ++h) {
        if (kk == 0 && h == 0) { S_WAITCNT_VM(0); }  // tile kt fully resident (once/K-tile)
        __builtin_amdgcn_s_barrier();
        LDS_FENCE();
        const int ph = kk * 2 + h;
        stA(kt + 1, ph);  // prefetch next tile (lands before next K-tile's vmcnt gate)
        stB(kt + 1, ph);
        const int rc = ((kk * 4 + lk) ^ (lr & 7)) << 4;  // swizzled 16B-chunk offset
        bf16x8 af[4];
#pragma unroll
        for (int i = 0; i < 4; ++i)
          af[i] = *reinterpret_cast<const bf16x8*>(Ab + (wm * 128 + (h * 4 + i) * 16 + lr) * 128 + rc);
        if (h == 0) {
#pragma unroll
          for (int j = 0; j < 4; ++j)
            bfr[j] = *reinterpret_cast<const bf16x8*>(Bb + (wn * 64 + j * 16 + lr) * 128 + rc);
        }
        __builtin_amdgcn_s_setprio(1);
#pragma unroll
        for (int i = 0; i < 4; ++i)
#pragma unroll
          for (int j = 0; j < 4; ++j)
            acc[h * 4 + i][j] = __builtin_amdgcn_mfma_f32_16x16x32_bf16(af[i], bfr[j], acc[h * 4 + i][j], 0, 0, 0);
        __builtin_amdgcn_s_setprio(0);
      }
    }
  }
#pragma unroll
  for (int i = 0; i < 8; ++i)
#pragma unroll
    for (int j = 0; j < 4; ++j)
#pragma unroll
      for (int r = 0; r < 4; ++r) {
        int row = m0 + wm * 128 + i * 16 + lk * 4 + r;
        int col = n0 + wn * 64 + j * 16 + lr;
        if constexpr (sizeof(OT) == 4)
          C[(size_t)row * Ncols + col] = acc[i][j][r];
        else
          C[(size_t)row * Ncols + col] = (bf16)acc[i][j][r];
      }
}

// ---------------- 2-phase GEMM (round-6 verified) for O projection ------
template <int BM, typename OT>
__global__ __launch_bounds__(512) void k_gemm2(const bf16* __restrict__ A, const bf16* __restrict__ Bt,
                                               OT* __restrict__ C, int N, int Kd) {
  constexpr int NA = (BM / 16) * 2;
  constexpr int NB = 16;
  constexpr int NST = NA + NB;
  constexpr int NSW = NST / 8;
  constexpr int WM = BM / 4;
  constexpr int RG = WM / 16;
  __shared__ __align__(16) bf16 sAB[2][NST * 512];
  const int t = threadIdx.x, w = t >> 6, l = t & 63;
  const int lr = l & 15, lk = l >> 4;
  const int gx = gridDim.x;
  const int nwg = gx * gridDim.y;
  const int flat = blockIdx.y * gx + blockIdx.x;
  const int vid = (flat & 7) * (nwg >> 3) + (flat >> 3);
  const int m0 = (vid % gx) * BM, n0 = (vid / gx) * 128;
  const int wm = w >> 1, wn = w & 1;
  const int srow = l >> 2;
  const int lchunk = (l & 3) ^ (((l >> 5) & 1) << 1);
  const int rdoff = lr * 64 + ((lk * 16) ^ ((lr >> 3) << 5));
  const int nkt = Kd >> 6;
  char* lds = (char*)sAB;

  auto stage = [&](int kt, int buf) {
    const int k0 = kt << 6;
#pragma unroll
    for (int u = 0; u < NSW; ++u) {
      const int s = w * NSW + u;
      const bf16* src;
      if (s < NA)
        src = A + (size_t)(m0 + (s >> 1) * 16 + srow) * Kd + k0 + (s & 1) * 32 + lchunk * 8;
      else
        src = Bt + (size_t)(n0 + ((s - NA) >> 1) * 16 + srow) * Kd + k0 + ((s - NA) & 1) * 32 + lchunk * 8;
      gload_lds16(src, lds + buf * (NST * 1024) + s * 1024);
    }
  };

  f32x4 acc[RG][4] = {};
  stage(0, 0);
  stage(1, 1);
  if constexpr (NSW == 6) S_WAITCNT_VM(6); else S_WAITCNT_VM(4);
  __builtin_amdgcn_s_barrier();
  int c = 0;
  for (int kt = 0; kt < nkt; ++kt) {
    __builtin_amdgcn_sched_barrier(0);
    const char* base = lds + c * (NST * 1024);
    bf16x8 af[RG][2], bfr[4][2];
#pragma unroll
    for (int i = 0; i < RG; ++i)
#pragma unroll
      for (int kk = 0; kk < 2; ++kk)
        af[i][kk] = *reinterpret_cast<const bf16x8*>(base + ((wm * RG + i) * 2 + kk) * 1024 + rdoff);
#pragma unroll
    for (int j = 0; j < 4; ++j)
#pragma unroll
      for (int kk = 0; kk < 2; ++kk)
        bfr[j][kk] = *reinterpret_cast<const bf16x8*>(base + (NA + (wn * 4 + j) * 2 + kk) * 1024 + rdoff);
    __builtin_amdgcn_s_setprio(1);
#pragma unroll
    for (int i = 0; i < RG; ++i)
#pragma unroll
      for (int j = 0; j < 4; ++j) {
        acc[i][j] = __builtin_amdgcn_mfma_f32_16x16x32_bf16(af[i][0], bfr[j][0], acc[i][j], 0, 0, 0);
        acc[i][j] = __builtin_amdgcn_mfma_f32_16x16x32_bf16(af[i][1], bfr[j][1], acc[i][j], 0, 0, 0);
      }
    __builtin_amdgcn_s_setprio(0);
    __builtin_amdgcn_sched_barrier(0);
    asm volatile("" ::: "memory");
    __builtin_amdgcn_s_barrier();
    if (kt + 2 < nkt) stage(kt + 2, c);
    if (kt + 1 < nkt) {
      if (kt + 2 < nkt) {
        if constexpr (NSW == 6) S_WAITCNT_VM(6); else S_WAITCNT_VM(4);
      } else {
        S_WAITCNT_VM(0);
      }
      asm volatile("" ::: "memory");
      __builtin_amdgcn_s_barrier();
    }
    c ^= 1;
  }
#pragma unroll
  for (int i = 0; i < RG; ++i)
#pragma unroll
    for (int j = 0; j < 4; ++j)
#pragma unroll
      for (int r = 0; r < 4; ++r) {
        int row = m0 + wm * WM + i * 16 + lk * 4 + r;
        int col = n0 + wn * 64 + j * 16 + lr;
        if constexpr (sizeof(OT) == 4)
          C[(size_t)row * N + col] = acc[i][j][r];
        else
          C[(size_t)row * N + col] = (bf16)acc[i][j][r];
      }
}

// ---------------- RoPE in place (optionally folds score scale into Q) ----------------
__global__ void k_rope(bf16* __restrict__ X, const float* __restrict__ cs, const float* __restrict__ sn,
                       int nh, int rowstride, float scale, int total) {
  int idx = blockIdx.x * blockDim.x + threadIdx.x;
  if (idx >= total) return;
  int d = idx & 63;
  int th = idx >> 6;
  int h = th % nh;
  int tok = th / nh;
  size_t base = (size_t)tok * rowstride + h * 128;
  float c = cs[tok * 128 + d], s = sn[tok * 128 + d];
  float x1 = (float)X[base + d];
  float x2 = (float)X[base + d + 64];
  X[base + d] = (bf16)((x1 * c - x2 * s) * scale);
  X[base + d + 64] = (bf16)((x2 * c + x1 * s) * scale);
}

// ---------------- causal flash attention: 8 waves = 4 q-groups x 2 kv-halves ----------
// (round-12 verified: est ~64us) Block = 512 thr; wq owns 32 q-rows, wk owns one 32-kv
// half. Paired segments {p, 15-p} -> uniform 34 tiles/block; grid 256, 2 waves/SIMD.
__global__ __launch_bounds__(512) void k_attn(const bf16* __restrict__ Q, const bf16* __restrict__ KV,
                                              const bf16* __restrict__ Vt, bf16* __restrict__ O) {
  constexpr int S = 2048, HD = 128, QSTR = 3072, OSTR = 2048;
  __shared__ __align__(16) char smem[81920];
  const int bid = blockIdx.x;
  const int vid = (bid & 7) * 32 + (bid >> 3);  // XCD swizzle: one (b,kvh) per XCD
  const int p = vid & 7, bh = vid >> 3;
  const int h = bh & 15, b = bh >> 4;
  const int t = threadIdx.x, w = t >> 6, l = t & 63;
  const int wq = w & 3, wk = w >> 2;
  const int lr = l & 15, lk = l >> 4;
  const int kvh = h >> 2;
  const int swz = (lr & 7) << 4;

  const char* kbase = (const char*)(KV + (size_t)b * S * QSTR + kvh * HD);
  const int krow_l = w * 8 + (l >> 4);
  const int kcol_l = (l & 15) << 4;
  const char* vtbase = (const char*)(Vt + (size_t)(b * 4 + kvh) * HD * S);
  const int vrow_l = w * 16 + (l >> 3);
  const int vcol_l = (l & 7) << 4;
  auto stage = [&](int kvb, int buf) {
#pragma unroll
    for (int c = 0; c < 2; ++c) {
      const int krow = krow_l + c * 4;
      gload_lds16(kbase + (size_t)(kvb + krow) * (QSTR * 2) + (kcol_l ^ ((krow & 7) << 4)),
                  smem + buf * 16384 + (w * 2 + c) * 1024);
      const int vrow = vrow_l + c * 8;
      gload_lds16(vtbase + (size_t)vrow * (S * 2) + kvb * 2 + (vcol_l ^ ((vrow & 7) << 4)),
                  smem + 32768 + buf * 16384 + (w * 2 + c) * 1024);
    }
  };
  char* sPb = smem + 65536 + w * 1280;  // per-wave [16 rows][40 cols] bf16 (80B rows)

  for (int seg = 0; seg < 2; ++seg) {
    const int qtl = seg ? (15 - p) : p;
    const int qw = qtl * 128 + wq * 32;
    const int qlast = qw + 31;
    const int ntiles = (qtl + 1) * 2;
    int cur = 0;
    __syncthreads();  // prior segment's merge reads / last-tile reads complete
    stage(0, 0);
    bf16x8 qf[2][4];
#pragma unroll
    for (int rg = 0; rg < 2; ++rg) {
      const bf16* Qp = Q + (size_t)(b * S + qw + rg * 16 + lr) * QSTR + h * HD + lk * 8;
#pragma unroll
      for (int i = 0; i < 4; ++i) qf[rg][i] = *reinterpret_cast<const bf16x8*>(Qp + i * 32);
    }
    f32x4 oacc[2][8] = {};
    float mrow[2][4] = {{-1e30f, -1e30f, -1e30f, -1e30f}, {-1e30f, -1e30f, -1e30f, -1e30f}};
    float lsum[2][4] = {};
    __syncthreads();  // tile 0 resident
    for (int tt = 0; tt < ntiles; ++tt) {
      const int kvb = tt * 64;
      if (tt + 1 < ntiles) stage(kvb + 64, cur ^ 1);  // prefetch hides under compute
      const char* sKc = smem + cur * 16384;
      const char* sVc = smem + 32768 + cur * 16384;
      const int col0 = kvb + wk * 32;
      if (col0 <= qlast) {
        float pm[2][2][4];
#pragma unroll
        for (int c = 0; c < 2; ++c) {
          f32x4 s0 = {}, s1 = {};
#pragma unroll
          for (int kf = 0; kf < 4; ++kf) {
            bf16x8 kf8 = *reinterpret_cast<const bf16x8*>(
                sKc + (wk * 32 + c * 16 + lr) * 256 + (((kf * 64) + (lk << 4)) ^ swz));
            s0 = __builtin_amdgcn_mfma_f32_16x16x32_bf16(qf[0][kf], kf8, s0, 0, 0, 0);
            s1 = __builtin_amdgcn_mfma_f32_16x16x32_bf16(qf[1][kf], kf8, s1, 0, 0, 0);
          }
#pragma unroll
          for (int r = 0; r < 4; ++r) { pm[0][c][r] = s0[r]; pm[1][c][r] = s1[r]; }
        }
        if (col0 + 31 > qw) {
#pragma unroll
          for (int rg = 0; rg < 2; ++rg)
#pragma unroll
            for (int c = 0; c < 2; ++c) {
              const int col = col0 + c * 16 + lr;
#pragma unroll
              for (int r = 0; r < 4; ++r)
                if (col > qw + rg * 16 + lk * 4 + r) pm[rg][c][r] = -1e38f;
            }
        }
        float pmax[2][4];
#pragma unroll
        for (int rg = 0; rg < 2; ++rg)
#pragma unroll
          for (int r = 0; r < 4; ++r) pmax[rg][r] = fmaxf(pm[rg][0][r], pm[rg][1][r]);
        bool hi = false;
#pragma unroll
        for (int rg = 0; rg < 2; ++rg)
#pragma unroll
          for (int r = 0; r < 4; ++r) hi |= (pmax[rg][r] > mrow[rg][r] + 8.f);
        if (__any(hi)) {
          float mx[2][4];
#pragma unroll
          for (int rg = 0; rg < 2; ++rg)
#pragma unroll
            for (int r = 0; r < 4; ++r) mx[rg][r] = pmax[rg][r];
#pragma unroll
          for (int off = 1; off < 16; off <<= 1)
#pragma unroll
            for (int rg = 0; rg < 2; ++rg)
#pragma unroll
              for (int r = 0; r < 4; ++r) mx[rg][r] = fmaxf(mx[rg][r], __shfl_xor(mx[rg][r], off));
#pragma unroll
          for (int rg = 0; rg < 2; ++rg)
#pragma unroll
            for (int r = 0; r < 4; ++r) {
              float mn = fmaxf(mrow[rg][r], mx[rg][r]);
              float fac = fexp2(mrow[rg][r] - mn);
              mrow[rg][r] = mn;
              lsum[rg][r] *= fac;
#pragma unroll
              for (int ch = 0; ch < 8; ++ch) oacc[rg][ch][r] *= fac;
            }
        }
#pragma unroll
        for (int rg = 0; rg < 2; ++rg) {
#pragma unroll
          for (int c = 0; c < 2; ++c)
#pragma unroll
            for (int r = 0; r < 4; ++r) pm[rg][c][r] = fexp2(pm[rg][c][r] - mrow[rg][r]);
#pragma unroll
          for (int r = 0; r < 4; ++r) lsum[rg][r] += pm[rg][0][r] + pm[rg][1][r];
        }
        bf16x8 pf[2];
#pragma unroll
        for (int rg = 0; rg < 2; ++rg) {
#pragma unroll
          for (int c = 0; c < 2; ++c)
#pragma unroll
            for (int r = 0; r < 4; ++r)
              *(bf16*)(sPb + (lk * 4 + r) * 80 + (c * 16 + lr) * 2) = (bf16)pm[rg][c][r];
          pf[rg] = *reinterpret_cast<const bf16x8*>(sPb + lr * 80 + lk * 16);
        }
#pragma unroll
        for (int ch = 0; ch < 8; ++ch) {
          bf16x8 vf = *reinterpret_cast<const bf16x8*>(
              sVc + (ch * 16 + lr) * 128 + ((wk * 64 + (lk << 4)) ^ swz));
          oacc[0][ch] = __builtin_amdgcn_mfma_f32_16x16x32_bf16(pf[0], vf, oacc[0][ch], 0, 0, 0);
          oacc[1][ch] = __builtin_amdgcn_mfma_f32_16x16x32_bf16(pf[1], vf, oacc[1][ch], 0, 0, 0);
        }
      }
      __syncthreads();
      cur ^= 1;
    }
#pragma unroll
    for (int off = 1; off < 16; off <<= 1)
#pragma unroll
      for (int rg = 0; rg < 2; ++rg)
#pragma unroll
        for (int r = 0; r < 4; ++r) lsum[rg][r] += __shfl_xor(lsum[rg][r], off);
    float* ob = (float*)smem;
    float* mlb = (float*)(smem + 65536);
    if (wk == 1) {
#pragma unroll
      for (int rg = 0; rg < 2; ++rg) {
#pragma unroll
        for (int ch = 0; ch < 8; ++ch)
          *reinterpret_cast<f32x4*>(&ob[wq * 4096 + l * 64 + (rg * 8 + ch) * 4]) = oacc[rg][ch];
#pragma unroll
        for (int r = 0; r < 4; ++r) {
          mlb[wq * 1024 + l * 16 + rg * 8 + r] = mrow[rg][r];
          mlb[wq * 1024 + l * 16 + rg * 8 + 4 + r] = lsum[rg][r];
        }
      }
    }
    __syncthreads();
    if (wk == 0) {
      float sc0[2][4], sc1[2][4];
#pragma unroll
      for (int rg = 0; rg < 2; ++rg)
#pragma unroll
        for (int r = 0; r < 4; ++r) {
          float m1 = mlb[wq * 1024 + l * 16 + rg * 8 + r];
          float l1 = mlb[wq * 1024 + l * 16 + rg * 8 + 4 + r];
          float m = fmaxf(mrow[rg][r], m1);
          float w0 = fexp2(mrow[rg][r] - m), w1 = fexp2(m1 - m);
          float inv = 1.0f / (lsum[rg][r] * w0 + l1 * w1);
          sc0[rg][r] = w0 * inv;
          sc1[rg][r] = w1 * inv;
        }
#pragma unroll
      for (int rg = 0; rg < 2; ++rg) {
        bf16* Op = O + (size_t)(b * S + qw + rg * 16) * OSTR + h * HD;
#pragma unroll
        for (int ch = 0; ch < 8; ++ch) {
          f32x4 o1 = *reinterpret_cast<const f32x4*>(&ob[wq * 4096 + l * 64 + (rg * 8 + ch) * 4]);
#pragma unroll
          for (int r = 0; r < 4; ++r)
            Op[(size_t)(lk * 4 + r) * OSTR + ch * 16 + lr] =
                (bf16)(oacc[rg][ch][r] * sc0[rg][r] + o1[r] * sc1[rg][r]);
        }
      }
    }
  }
}

extern "C" void kernel_launch(void* const* d_in, const int* in_sizes, int n_in,
                              void* d_out, int out_size, void* d_ws, size_t ws_size,
                              hipStream_t stream) {
  const float* hs = (const float*)d_in[0];
  // d_in[1] = attention_mask: pure causal, applied analytically
  const float* cosb = (const float*)d_in[2];
  const float* sinb = (const float*)d_in[3];
  const float* Wq = (const float*)d_in[4];
  const float* Wk = (const float*)d_in[5];
  const float* Wv = (const float*)d_in[6];
  const float* Wo = (const float*)d_in[7];
  float* out = (float*)d_out;

  constexpr int B = 2, S = 2048, H = 2048, NH = 16, NKV = 4, HD = 128;
  constexpr int T = B * S;
  constexpr size_t MB = 1024 * 1024;

  // Workspace plan (d_ws 24 MiB):
  //   d_ws[ 0:16M) : Xb (bf16 X), reused as Ob after QKV projection
  //   d_ws[16:24M) : WtQ (8MB) -> later WtO (8MB)
  //   d_out[ 0:24M): Cqkv bf16 [4096][3072] (Q | K | V)
  //   d_out[24:28M): Vt [8][128][2048]
  //   d_out[28:32M): WtKV [1024][2048]
  const size_t ws_need = 24 * MB;
  if (ws_size < ws_need) {
    k_diag<<<1, 64, 0, stream>>>(out, 1000.0f + (float)(ws_size / MB));
    return;
  }
  bf16* Xb = (bf16*)d_ws;
  bf16* WtQ = (bf16*)((char*)d_ws + 16 * MB);  // also WtO slot later
  bf16* Ob = Xb;
  bf16* Cqkv = (bf16*)d_out;
  bf16* Vtb = (bf16*)((char*)d_out + 24 * MB);
  bf16* WtKV = (bf16*)((char*)d_out + 28 * MB);

  k_cvt_bf16<<<T * H / 4 / 256, 256, 0, stream>>>(hs, Xb, T * H / 4);

  k_transpose_w<<<dim3(H / 32, H / 32), 256, 0, stream>>>(Wq, WtQ, H, H);
  k_transpose_w<<<dim3(H / 32, (NKV * HD) / 32), 256, 0, stream>>>(Wk, WtKV, H, NKV * HD);
  k_transpose_w<<<dim3(H / 32, (NKV * HD) / 32), 256, 0, stream>>>(Wv, WtKV + (size_t)(NKV * HD) * H, H, NKV * HD);

  // fused QKV projection: C[4096][3072], grid 16x12 = 192 blocks, 2D XCD supertile
  k_gemm4<bf16><<<dim3(16, 12), 512, 0, stream>>>(Xb, WtQ, WtKV, 2048, Cqkv, 3072, H);

  // V -> Vt (V gets no RoPE)
  k_transpose_v<<<dim3(S / 32, HD / 32, B * NKV), 256, 0, stream>>>(Cqkv, Vtb);

  // RoPE; Q folds log2(e)/sqrt(HD) so QK^T lands in log2 domain
  const float qscale = 0.12751743f;  // log2(e) / sqrt(128)
  k_rope<<<(T * NH * 64) / 256, 256, 0, stream>>>(Cqkv, cosb, sinb, NH, 3072, qscale, T * NH * 64);
  k_rope<<<(T * NKV * 64) / 256, 256, 0, stream>>>(Cqkv + 2048, cosb, sinb, NKV, 3072, 1.0f, T * NKV * 64);

  // Attention: 256 blocks x 512 threads (8 waves: 4 q-groups x 2 kv-halves)
  k_attn<<<256, 512, 0, stream>>>(Cqkv, Cqkv + 2048, Vtb, Ob);

  // O projection: reads only d_ws (Ob, WtO), writes all of d_out; full 256-block fill
  k_transpose_w<<<dim3(H / 32, H / 32), 256, 0, stream>>>(Wo, WtQ, H, H);
  k_gemm2<256, float><<<dim3(16, 16), 512, 0, stream>>>(Ob, WtQ, out, H, H);
}

// Round 14
// 210.186 us; speedup vs baseline: 1.3372x; 1.0147x over previous
//
#include <hip/hip_runtime.h>
#include <hip/hip_bf16.h>

typedef __bf16 bf16;
typedef __bf16 bf16x4 __attribute__((ext_vector_type(4)));
typedef __bf16 bf16x8 __attribute__((ext_vector_type(8)));
typedef float f32x4 __attribute__((ext_vector_type(4)));

__device__ __forceinline__ void gload_lds16(const void* g, void* l) {
  __builtin_amdgcn_global_load_lds((__attribute__((address_space(1))) void*)(g),
                                   (__attribute__((address_space(3))) void*)(l), 16, 0, 0);
}
// raw 2^x (v_exp_f32 IS exp2)
__device__ __forceinline__ float fexp2(float x) {
  float r;
  asm volatile("v_exp_f32 %0, %1" : "=v"(r) : "v"(x));
  return r;
}
#define S_WAITCNT_VM(n) asm volatile("s_waitcnt vmcnt(" #n ")" ::: "memory")
#define LDS_FENCE() asm volatile("" ::: "memory")

// ---------------- diagnostic: encode ws_size into output if workspace too small ----
__global__ void k_diag(float* __restrict__ o, float v) { o[threadIdx.x] = v; }

// ---------------- fp32 -> bf16 convert (vectorized) ----------------
__global__ void k_cvt_bf16(const float* __restrict__ x, bf16* __restrict__ y, int n4) {
  int i = blockIdx.x * blockDim.x + threadIdx.x;
  if (i < n4) {
    float4 v = reinterpret_cast<const float4*>(x)[i];
    bf16x4 o = {(bf16)v.x, (bf16)v.y, (bf16)v.z, (bf16)v.w};
    reinterpret_cast<bf16x4*>(y)[i] = o;
  }
}

// ---------------- W (K x N fp32, row-major) -> Wt (N x K bf16) ----------------
__global__ void k_transpose_w(const float* __restrict__ W, bf16* __restrict__ Wt, int K, int N) {
  __shared__ float tile[32][33];
  int kb = blockIdx.x * 32, nb = blockIdx.y * 32;
  int tx = threadIdx.x & 31, ty = threadIdx.x >> 5;
#pragma unroll
  for (int i = 0; i < 32; i += 8)
    tile[ty + i][tx] = W[(size_t)(kb + ty + i) * N + nb + tx];
  __syncthreads();
#pragma unroll
  for (int i = 0; i < 32; i += 8)
    Wt[(size_t)(nb + ty + i) * K + kb + tx] = (bf16)tile[tx][ty + i];
}

// ---------------- V (cols 2560.. of Cqkv, stride 3072) -> Vt[b][kvh][HD][S] ----------------
__global__ void k_transpose_v(const bf16* __restrict__ Cq, bf16* __restrict__ Vt) {
  __shared__ bf16 tile[32][34];
  constexpr int S = 2048, CSTR = 3072;
  int sb = blockIdx.x * 32, db = blockIdx.y * 32, bh = blockIdx.z;  // bh = b*4+kvh
  int b = bh >> 2, kvh = bh & 3;
  int tx = threadIdx.x & 31, ty = threadIdx.x >> 5;
  const bf16* src = Cq + (size_t)b * S * CSTR + 2560 + kvh * 128;
#pragma unroll
  for (int i = 0; i < 32; i += 8)
    tile[ty + i][tx] = src[(size_t)(sb + ty + i) * CSTR + db + tx];
  __syncthreads();
  bf16* dst = Vt + (size_t)bh * 128 * S;
#pragma unroll
  for (int i = 0; i < 32; i += 8)
    dst[(size_t)(db + ty + i) * S + sb + tx] = tile[tx][ty + i];
}

// ---------------- k_gemm4: 256x256, 4-phase K-loop (round-13 verified) ----------------
template <typename OT>
__global__ __launch_bounds__(512) void k_gemm4(const bf16* __restrict__ A,
                                               const bf16* __restrict__ B0,
                                               const bf16* __restrict__ B1, int nsplit,
                                               OT* __restrict__ C, int Ncols, int Kd) {
  __shared__ __align__(16) char lds[131072];
  const int t = threadIdx.x, w = t >> 6, l = t & 63;
  const int lr = l & 15, lk = l >> 4;
  const int gx = gridDim.x;
  const int flat = blockIdx.y * gx + blockIdx.x;
  const int xcd = flat & 7, local = flat >> 3;
  const int mi = (xcd & 3) * (gx >> 2) + (local & ((gx >> 2) - 1));
  const int ni = (xcd >> 2) * (gridDim.y >> 1) + (local >> 2);
  const int m0 = mi * 256, n0 = ni * 256;
  const int wm = w >> 2, wn = w & 3;
  const bf16* Bt = (n0 < nsplit) ? B0 + (size_t)n0 * Kd : B1 + (size_t)(n0 - nsplit) * Kd;
  const int nkt = Kd >> 6;
  const int srow8 = l >> 3;
  const int sk = ((l & 7) ^ srow8) * 8;  // inverse-swizzled global k-chunk
  auto stA = [&](int kt, int g) {
    if (kt >= nkt) return;
    const bf16* s = A + (size_t)(m0 + w * 32 + g * 8 + srow8) * Kd + (kt << 6) + sk;
    gload_lds16(s, lds + (kt & 1) * 32768 + (w * 32 + g * 8) * 128);
  };
  auto stB = [&](int kt, int g) {
    if (kt >= nkt) return;
    const bf16* s = Bt + (size_t)(w * 32 + g * 8 + srow8) * Kd + (kt << 6) + sk;
    gload_lds16(s, lds + 65536 + (kt & 1) * 32768 + (w * 32 + g * 8) * 128);
  };

  f32x4 acc[8][4] = {};
#pragma unroll
  for (int g = 0; g < 4; ++g) { stA(0, g); stB(0, g); }

  for (int kt = 0; kt < nkt; ++kt) {
    const char* Ab = lds + (kt & 1) * 32768;
    const char* Bb = lds + 65536 + (kt & 1) * 32768;
    bf16x8 bfr[4];
#pragma unroll
    for (int kk = 0; kk < 2; ++kk) {
#pragma unroll
      for (int h = 0; h < 2; ++h) {
        if (kk == 0 && h == 0) { S_WAITCNT_VM(0); }  // tile kt resident (once/K-tile)
        __builtin_amdgcn_s_barrier();
        LDS_FENCE();
        const int ph = kk * 2 + h;
        stA(kt + 1, ph);
        stB(kt + 1, ph);
        const int rc = ((kk * 4 + lk) ^ (lr & 7)) << 4;
        bf16x8 af[4];
#pragma unroll
        for (int i = 0; i < 4; ++i)
          af[i] = *reinterpret_cast<const bf16x8*>(Ab + (wm * 128 + (h * 4 + i) * 16 + lr) * 128 + rc);
        if (h == 0) {
#pragma unroll
          for (int j = 0; j < 4; ++j)
            bfr[j] = *reinterpret_cast<const bf16x8*>(Bb + (wn * 64 + j * 16 + lr) * 128 + rc);
        }
        __builtin_amdgcn_s_setprio(1);
#pragma unroll
        for (int i = 0; i < 4; ++i)
#pragma unroll
          for (int j = 0; j < 4; ++j)
            acc[h * 4 + i][j] = __builtin_amdgcn_mfma_f32_16x16x32_bf16(af[i], bfr[j], acc[h * 4 + i][j], 0, 0, 0);
        __builtin_amdgcn_s_setprio(0);
      }
    }
  }
#pragma unroll
  for (int i = 0; i < 8; ++i)
#pragma unroll
    for (int j = 0; j < 4; ++j)
#pragma unroll
      for (int r = 0; r < 4; ++r) {
        int row = m0 + wm * 128 + i * 16 + lk * 4 + r;
        int col = n0 + wn * 64 + j * 16 + lr;
        if constexpr (sizeof(OT) == 4)
          C[(size_t)row * Ncols + col] = acc[i][j][r];
        else
          C[(size_t)row * Ncols + col] = (bf16)acc[i][j][r];
      }
}

// ---------------- k_gemm5: 128x256 gemm4-style, full 256-block fill (O-proj) ----------
// 8 waves 2M x 4N, wave tile 64x64, acc[4][4]. 2 phases/K-tile: 8 ds_read + 16 MFMA.
// 6 gloads/wave/K-tile (3+3). One vmcnt(0) per K-tile. LDS 96KB. XCD swizzle: each
// XCD owns one 256-col B panel (1MB L2-resident).
template <typename OT>
__global__ __launch_bounds__(512) void k_gemm5(const bf16* __restrict__ A, const bf16* __restrict__ Bt,
                                               OT* __restrict__ C, int Ncols, int Kd) {
  __shared__ __align__(16) char lds[98304];  // A 2x16KB @0, B 2x32KB @32768
  const int t = threadIdx.x, w = t >> 6, l = t & 63;
  const int lr = l & 15, lk = l >> 4;
  const int gx = gridDim.x;  // 32 M-tiles; gridDim.y = 8 N-tiles
  const int flat = blockIdx.y * gx + blockIdx.x;
  const int vid = (flat & 7) * 32 + (flat >> 3);  // XCD x -> n-column x (bijective 8x32)
  const int m0 = (vid & 31) * 128, n0 = (vid >> 5) * 256;
  const int wm = w >> 2, wn = w & 3;
  const int nkt = Kd >> 6;
  const int srow8 = l >> 3;
  const int sk = ((l & 7) ^ srow8) * 8;
  auto stA = [&](int kt, int g) {
    if (kt >= nkt) return;
    const bf16* s = A + (size_t)(m0 + w * 16 + g * 8 + srow8) * Kd + (kt << 6) + sk;
    gload_lds16(s, lds + (kt & 1) * 16384 + (w * 16 + g * 8) * 128);
  };
  auto stB = [&](int kt, int g) {
    if (kt >= nkt) return;
    const bf16* s = Bt + (size_t)(n0 + w * 32 + g * 8 + srow8) * Kd + (kt << 6) + sk;
    gload_lds16(s, lds + 32768 + (kt & 1) * 32768 + (w * 32 + g * 8) * 128);
  };

  f32x4 acc[4][4] = {};
  stA(0, 0); stA(0, 1); stB(0, 0); stB(0, 1); stB(0, 2); stB(0, 3);

  for (int kt = 0; kt < nkt; ++kt) {
    const char* Ab = lds + (kt & 1) * 16384;
    const char* Bb = lds + 32768 + (kt & 1) * 32768;
#pragma unroll
    for (int kk = 0; kk < 2; ++kk) {
      if (kk == 0) { S_WAITCNT_VM(0); }
      __builtin_amdgcn_s_barrier();
      LDS_FENCE();
      if (kk == 0) { stA(kt + 1, 0); stA(kt + 1, 1); stB(kt + 1, 0); }
      else { stB(kt + 1, 1); stB(kt + 1, 2); stB(kt + 1, 3); }
      const int rc = ((kk * 4 + lk) ^ (lr & 7)) << 4;
      bf16x8 af[4], bfr[4];
#pragma unroll
      for (int i = 0; i < 4; ++i)
        af[i] = *reinterpret_cast<const bf16x8*>(Ab + (wm * 64 + i * 16 + lr) * 128 + rc);
#pragma unroll
      for (int j = 0; j < 4; ++j)
        bfr[j] = *reinterpret_cast<const bf16x8*>(Bb + (wn * 64 + j * 16 + lr) * 128 + rc);
      __builtin_amdgcn_s_setprio(1);
#pragma unroll
      for (int i = 0; i < 4; ++i)
#pragma unroll
        for (int j = 0; j < 4; ++j)
          acc[i][j] = __builtin_amdgcn_mfma_f32_16x16x32_bf16(af[i], bfr[j], acc[i][j], 0, 0, 0);
      __builtin_amdgcn_s_setprio(0);
    }
  }
#pragma unroll
  for (int i = 0; i < 4; ++i)
#pragma unroll
    for (int j = 0; j < 4; ++j)
#pragma unroll
      for (int r = 0; r < 4; ++r) {
        int row = m0 + wm * 64 + i * 16 + lk * 4 + r;
        int col = n0 + wn * 64 + j * 16 + lr;
        if constexpr (sizeof(OT) == 4)
          C[(size_t)row * Ncols + col] = acc[i][j][r];
        else
          C[(size_t)row * Ncols + col] = (bf16)acc[i][j][r];
      }
}

// ---------------- RoPE in place (optionally folds score scale into Q) ----------------
__global__ void k_rope(bf16* __restrict__ X, const float* __restrict__ cs, const float* __restrict__ sn,
                       int nh, int rowstride, float scale, int total) {
  int idx = blockIdx.x * blockDim.x + threadIdx.x;
  if (idx >= total) return;
  int d = idx & 63;
  int th = idx >> 6;
  int h = th % nh;
  int tok = th / nh;
  size_t base = (size_t)tok * rowstride + h * 128;
  float c = cs[tok * 128 + d], s = sn[tok * 128 + d];
  float x1 = (float)X[base + d];
  float x2 = (float)X[base + d + 64];
  X[base + d] = (bf16)((x1 * c - x2 * s) * scale);
  X[base + d + 64] = (bf16)((x2 * c + x1 * s) * scale);
}

// ---------------- causal flash attention: 8 waves = 4 q-groups x 2 kv-halves ----------
// (round-12/13 verified structure; round-14: conflict-free merge layout)
__global__ __launch_bounds__(512) void k_attn(const bf16* __restrict__ Q, const bf16* __restrict__ KV,
                                              const bf16* __restrict__ Vt, bf16* __restrict__ O) {
  constexpr int S = 2048, HD = 128, QSTR = 3072, OSTR = 2048;
  __shared__ __align__(16) char smem[81920];
  const int bid = blockIdx.x;
  const int vid = (bid & 7) * 32 + (bid >> 3);  // XCD swizzle: one (b,kvh) per XCD
  const int p = vid & 7, bh = vid >> 3;
  const int h = bh & 15, b = bh >> 4;
  const int t = threadIdx.x, w = t >> 6, l = t & 63;
  const int wq = w & 3, wk = w >> 2;
  const int lr = l & 15, lk = l >> 4;
  const int kvh = h >> 2;
  const int swz = (lr & 7) << 4;

  const char* kbase = (const char*)(KV + (size_t)b * S * QSTR + kvh * HD);
  const int krow_l = w * 8 + (l >> 4);
  const int kcol_l = (l & 15) << 4;
  const char* vtbase = (const char*)(Vt + (size_t)(b * 4 + kvh) * HD * S);
  const int vrow_l = w * 16 + (l >> 3);
  const int vcol_l = (l & 7) << 4;
  auto stage = [&](int kvb, int buf) {
#pragma unroll
    for (int c = 0; c < 2; ++c) {
      const int krow = krow_l + c * 4;
      gload_lds16(kbase + (size_t)(kvb + krow) * (QSTR * 2) + (kcol_l ^ ((krow & 7) << 4)),
                  smem + buf * 16384 + (w * 2 + c) * 1024);
      const int vrow = vrow_l + c * 8;
      gload_lds16(vtbase + (size_t)vrow * (S * 2) + kvb * 2 + (vcol_l ^ ((vrow & 7) << 4)),
                  smem + 32768 + buf * 16384 + (w * 2 + c) * 1024);
    }
  };
  char* sPb = smem + 65536 + w * 1280;  // per-wave [16 rows][40 cols] bf16 (80B rows)

  for (int seg = 0; seg < 2; ++seg) {
    const int qtl = seg ? (15 - p) : p;
    const int qw = qtl * 128 + wq * 32;
    const int qlast = qw + 31;
    const int ntiles = (qtl + 1) * 2;
    int cur = 0;
    __syncthreads();  // prior segment's merge reads / last-tile reads complete
    stage(0, 0);
    bf16x8 qf[2][4];
#pragma unroll
    for (int rg = 0; rg < 2; ++rg) {
      const bf16* Qp = Q + (size_t)(b * S + qw + rg * 16 + lr) * QSTR + h * HD + lk * 8;
#pragma unroll
      for (int i = 0; i < 4; ++i) qf[rg][i] = *reinterpret_cast<const bf16x8*>(Qp + i * 32);
    }
    f32x4 oacc[2][8] = {};
    float mrow[2][4] = {{-1e30f, -1e30f, -1e30f, -1e30f}, {-1e30f, -1e30f, -1e30f, -1e30f}};
    float lsum[2][4] = {};
    __syncthreads();  // tile 0 resident
    for (int tt = 0; tt < ntiles; ++tt) {
      const int kvb = tt * 64;
      if (tt + 1 < ntiles) stage(kvb + 64, cur ^ 1);  // prefetch hides under compute
      const char* sKc = smem + cur * 16384;
      const char* sVc = smem + 32768 + cur * 16384;
      const int col0 = kvb + wk * 32;
      if (col0 <= qlast) {
        float pm[2][2][4];
#pragma unroll
        for (int c = 0; c < 2; ++c) {
          f32x4 s0 = {}, s1 = {};
#pragma unroll
          for (int kf = 0; kf < 4; ++kf) {
            bf16x8 kf8 = *reinterpret_cast<const bf16x8*>(
                sKc + (wk * 32 + c * 16 + lr) * 256 + (((kf * 64) + (lk << 4)) ^ swz));
            s0 = __builtin_amdgcn_mfma_f32_16x16x32_bf16(qf[0][kf], kf8, s0, 0, 0, 0);
            s1 = __builtin_amdgcn_mfma_f32_16x16x32_bf16(qf[1][kf], kf8, s1, 0, 0, 0);
          }
#pragma unroll
          for (int r = 0; r < 4; ++r) { pm[0][c][r] = s0[r]; pm[1][c][r] = s1[r]; }
        }
        if (col0 + 31 > qw) {
#pragma unroll
          for (int rg = 0; rg < 2; ++rg)
#pragma unroll
            for (int c = 0; c < 2; ++c) {
              const int col = col0 + c * 16 + lr;
#pragma unroll
              for (int r = 0; r < 4; ++r)
                if (col > qw + rg * 16 + lk * 4 + r) pm[rg][c][r] = -1e38f;
            }
        }
        float pmax[2][4];
#pragma unroll
        for (int rg = 0; rg < 2; ++rg)
#pragma unroll
          for (int r = 0; r < 4; ++r) pmax[rg][r] = fmaxf(pm[rg][0][r], pm[rg][1][r]);
        bool hi = false;
#pragma unroll
        for (int rg = 0; rg < 2; ++rg)
#pragma unroll
          for (int r = 0; r < 4; ++r) hi |= (pmax[rg][r] > mrow[rg][r] + 8.f);
        if (__any(hi)) {
          float mx[2][4];
#pragma unroll
          for (int rg = 0; rg < 2; ++rg)
#pragma unroll
            for (int r = 0; r < 4; ++r) mx[rg][r] = pmax[rg][r];
#pragma unroll
          for (int off = 1; off < 16; off <<= 1)
#pragma unroll
            for (int rg = 0; rg < 2; ++rg)
#pragma unroll
              for (int r = 0; r < 4; ++r) mx[rg][r] = fmaxf(mx[rg][r], __shfl_xor(mx[rg][r], off));
#pragma unroll
          for (int rg = 0; rg < 2; ++rg)
#pragma unroll
            for (int r = 0; r < 4; ++r) {
              float mn = fmaxf(mrow[rg][r], mx[rg][r]);
              float fac = fexp2(mrow[rg][r] - mn);
              mrow[rg][r] = mn;
              lsum[rg][r] *= fac;
#pragma unroll
              for (int ch = 0; ch < 8; ++ch) oacc[rg][ch][r] *= fac;
            }
        }
#pragma unroll
        for (int rg = 0; rg < 2; ++rg) {
#pragma unroll
          for (int c = 0; c < 2; ++c)
#pragma unroll
            for (int r = 0; r < 4; ++r) pm[rg][c][r] = fexp2(pm[rg][c][r] - mrow[rg][r]);
#pragma unroll
          for (int r = 0; r < 4; ++r) lsum[rg][r] += pm[rg][0][r] + pm[rg][1][r];
        }
        bf16x8 pf[2];
#pragma unroll
        for (int rg = 0; rg < 2; ++rg) {
#pragma unroll
          for (int c = 0; c < 2; ++c)
#pragma unroll
            for (int r = 0; r < 4; ++r)
              *(bf16*)(sPb + (lk * 4 + r) * 80 + (c * 16 + lr) * 2) = (bf16)pm[rg][c][r];
          pf[rg] = *reinterpret_cast<const bf16x8*>(sPb + lr * 80 + lk * 16);
        }
#pragma unroll
        for (int ch = 0; ch < 8; ++ch) {
          bf16x8 vf = *reinterpret_cast<const bf16x8*>(
              sVc + (ch * 16 + lr) * 128 + ((wk * 64 + (lk << 4)) ^ swz));
          oacc[0][ch] = __builtin_amdgcn_mfma_f32_16x16x32_bf16(pf[0], vf, oacc[0][ch], 0, 0, 0);
          oacc[1][ch] = __builtin_amdgcn_mfma_f32_16x16x32_bf16(pf[1], vf, oacc[1][ch], 0, 0, 0);
        }
      }
      __syncthreads();
      cur ^= 1;
    }
#pragma unroll
    for (int off = 1; off < 16; off <<= 1)
#pragma unroll
      for (int rg = 0; rg < 2; ++rg)
#pragma unroll
        for (int r = 0; r < 4; ++r) lsum[rg][r] += __shfl_xor(lsum[rg][r], off);
    // ---- cross-half merge (conflict-free layout: lane-contiguous 16B) ----
    float* ob = (float*)smem;            // 64KB (dead K/V region)
    float* mlb = (float*)(smem + 65536); // 16KB (dead sP region)
    if (wk == 1) {
#pragma unroll
      for (int rg = 0; rg < 2; ++rg) {
#pragma unroll
        for (int ch = 0; ch < 8; ++ch)
          *reinterpret_cast<f32x4*>(&ob[wq * 4096 + (rg * 8 + ch) * 256 + l * 4]) = oacc[rg][ch];
#pragma unroll
        for (int r = 0; r < 4; ++r) {
          mlb[wq * 1024 + l * 16 + rg * 8 + r] = mrow[rg][r];
          mlb[wq * 1024 + l * 16 + rg * 8 + 4 + r] = lsum[rg][r];
        }
      }
    }
    __syncthreads();
    if (wk == 0) {
      float sc0[2][4], sc1[2][4];
#pragma unroll
      for (int rg = 0; rg < 2; ++rg)
#pragma unroll
        for (int r = 0; r < 4; ++r) {
          float m1 = mlb[wq * 1024 + l * 16 + rg * 8 + r];
          float l1 = mlb[wq * 1024 + l * 16 + rg * 8 + 4 + r];
          float m = fmaxf(mrow[rg][r], m1);
          float w0 = fexp2(mrow[rg][r] - m), w1 = fexp2(m1 - m);
          float inv = 1.0f / (lsum[rg][r] * w0 + l1 * w1);
          sc0[rg][r] = w0 * inv;
          sc1[rg][r] = w1 * inv;
        }
#pragma unroll
      for (int rg = 0; rg < 2; ++rg) {
        bf16* Op = O + (size_t)(b * S + qw + rg * 16) * OSTR + h * HD;
#pragma unroll
        for (int ch = 0; ch < 8; ++ch) {
          f32x4 o1 = *reinterpret_cast<const f32x4*>(&ob[wq * 4096 + (rg * 8 + ch) * 256 + l * 4]);
#pragma unroll
          for (int r = 0; r < 4; ++r)
            Op[(size_t)(lk * 4 + r) * OSTR + ch * 16 + lr] =
                (bf16)(oacc[rg][ch][r] * sc0[rg][r] + o1[r] * sc1[rg][r]);
        }
      }
    }
  }
}

extern "C" void kernel_launch(void* const* d_in, const int* in_sizes, int n_in,
                              void* d_out, int out_size, void* d_ws, size_t ws_size,
                              hipStream_t stream) {
  const float* hs = (const float*)d_in[0];
  // d_in[1] = attention_mask: pure causal, applied analytically
  const float* cosb = (const float*)d_in[2];
  const float* sinb = (const float*)d_in[3];
  const float* Wq = (const float*)d_in[4];
  const float* Wk = (const float*)d_in[5];
  const float* Wv = (const float*)d_in[6];
  const float* Wo = (const float*)d_in[7];
  float* out = (float*)d_out;

  constexpr int B = 2, S = 2048, H = 2048, NH = 16, NKV = 4, HD = 128;
  constexpr int T = B * S;
  constexpr size_t MB = 1024 * 1024;

  // Workspace plan (d_ws 24 MiB):
  //   d_ws[ 0:16M) : Xb (bf16 X), reused as Ob after QKV projection
  //   d_ws[16:24M) : WtQ (8MB) -> later WtO (8MB)
  //   d_out[ 0:24M): Cqkv bf16 [4096][3072] (Q | K | V)
  //   d_out[24:28M): Vt [8][128][2048]
  //   d_out[28:32M): WtKV [1024][2048]
  const size_t ws_need = 24 * MB;
  if (ws_size < ws_need) {
    k_diag<<<1, 64, 0, stream>>>(out, 1000.0f + (float)(ws_size / MB));
    return;
  }
  bf16* Xb = (bf16*)d_ws;
  bf16* WtQ = (bf16*)((char*)d_ws + 16 * MB);  // also WtO slot later
  bf16* Ob = Xb;
  bf16* Cqkv = (bf16*)d_out;
  bf16* Vtb = (bf16*)((char*)d_out + 24 * MB);
  bf16* WtKV = (bf16*)((char*)d_out + 28 * MB);

  k_cvt_bf16<<<T * H / 4 / 256, 256, 0, stream>>>(hs, Xb, T * H / 4);

  k_transpose_w<<<dim3(H / 32, H / 32), 256, 0, stream>>>(Wq, WtQ, H, H);
  k_transpose_w<<<dim3(H / 32, (NKV * HD) / 32), 256, 0, stream>>>(Wk, WtKV, H, NKV * HD);
  k_transpose_w<<<dim3(H / 32, (NKV * HD) / 32), 256, 0, stream>>>(Wv, WtKV + (size_t)(NKV * HD) * H, H, NKV * HD);

  // fused QKV projection: C[4096][3072], grid 16x12 = 192 blocks, 2D XCD supertile
  k_gemm4<bf16><<<dim3(16, 12), 512, 0, stream>>>(Xb, WtQ, WtKV, 2048, Cqkv, 3072, H);

  // V -> Vt (V gets no RoPE)
  k_transpose_v<<<dim3(S / 32, HD / 32, B * NKV), 256, 0, stream>>>(Cqkv, Vtb);

  // RoPE; Q folds log2(e)/sqrt(HD) so QK^T lands in log2 domain
  const float qscale = 0.12751743f;  // log2(e) / sqrt(128)
  k_rope<<<(T * NH * 64) / 256, 256, 0, stream>>>(Cqkv, cosb, sinb, NH, 3072, qscale, T * NH * 64);
  k_rope<<<(T * NKV * 64) / 256, 256, 0, stream>>>(Cqkv + 2048, cosb, sinb, NKV, 3072, 1.0f, T * NKV * 64);

  // Attention: 256 blocks x 512 threads (8 waves: 4 q-groups x 2 kv-halves)
  k_attn<<<256, 512, 0, stream>>>(Cqkv, Cqkv + 2048, Vtb, Ob);

  // O projection: k_gemm5 full 256-block fill (32 M-tiles x 8 N-tiles)
  k_transpose_w<<<dim3(H / 32, H / 32), 256, 0, stream>>>(Wo, WtQ, H, H);
  k_gemm5<float><<<dim3(32, 8), 512, 0, stream>>>(Ob, WtQ, out, H, H);
}